// Round 5
// baseline (3553.395 us; speedup 1.0000x reference)
//
#include <hip/hip_runtime.h>
#include <math.h>

#define NN 100000
#define NE 1600000
#define H 150
#define NG 256
#define NL 5
#define GH 200
#define HS 160          // padded bf16 row stride (elements)
#define LS 168          // LDS row stride in bf16 elems
#define CHN 1563        // ceil(NN/64)
#define SNB 98          // ceil(NN/1024)

typedef unsigned short u16;
typedef unsigned int   u32;
typedef __attribute__((ext_vector_type(8))) short bf16x8;
typedef __attribute__((ext_vector_type(4))) float f32x4;

__device__ __forceinline__ float bf2f(u32 lo16){ u32 t = lo16 << 16; return __builtin_bit_cast(float, t); }
__device__ __forceinline__ u16 f2bf(float f){
  u32 u = __builtin_bit_cast(u32, f);
  u += 0x7fffu + ((u >> 16) & 1u);
  return (u16)(u >> 16);
}
__device__ __forceinline__ u32 pack2(float a, float b){ return (u32)f2bf(a) | ((u32)f2bf(b) << 16); }
__device__ __forceinline__ float fast_sig(float x){
  float e = __expf(-x);
  return __builtin_amdgcn_rcpf(1.f + e);
}
__device__ __forceinline__ float fast_tanh(float x){
  float cx = fminf(fmaxf(x, -15.f), 15.f);
  float e = __expf(2.f*cx);
  return (e - 1.f) * __builtin_amdgcn_rcpf(e + 1.f);
}

// ---- CSR build ----
__global__ void k_hist(const int* __restrict__ ed, int* __restrict__ cnt){
  int e = blockIdx.x*256 + threadIdx.x;
  if (e < NE) atomicAdd(&cnt[ed[e]], 1);
}

__global__ __launch_bounds__(256) void k_scan1(const int* __restrict__ cnt, int* __restrict__ part){
  __shared__ int red[256];
  const int b = blockIdx.x, tid = threadIdx.x;
  const int base = b*1024;
  int s = 0;
  #pragma unroll
  for (int i = 0; i < 4; ++i){
    int idx = base + tid + i*256;
    s += (idx < NN) ? cnt[idx] : 0;
  }
  red[tid] = s; __syncthreads();
  for (int st = 128; st >= 1; st >>= 1){
    if (tid < st) red[tid] += red[tid+st];
    __syncthreads();
  }
  if (tid == 0) part[b] = red[0];
}

__global__ void k_scan2(int* __restrict__ part){
  const int t = threadIdx.x;
  int v0 = (2*t   < SNB) ? part[2*t]   : 0;
  int v1 = (2*t+1 < SNB) ? part[2*t+1] : 0;
  int s = v0 + v1, x = s;
  #pragma unroll
  for (int off = 1; off < 64; off <<= 1){
    int tt = __shfl_up(x, off);
    if (t >= off) x += tt;
  }
  int excl = x - s;
  if (2*t   < SNB) part[2*t]   = excl;
  if (2*t+1 < SNB) part[2*t+1] = excl + v0;
}

__global__ __launch_bounds__(1024) void k_scan3(const int* __restrict__ cnt,
        const int* __restrict__ part, int* __restrict__ rowptr, int* __restrict__ cursor){
  __shared__ int wsum[16];
  const int b = blockIdx.x, tid = threadIdx.x;
  const int wid = tid >> 6, lane = tid & 63;
  const int idx = b*1024 + tid;
  int v = (idx < NN) ? cnt[idx] : 0;
  int x = v;
  #pragma unroll
  for (int off = 1; off < 64; off <<= 1){
    int t = __shfl_up(x, off);
    if (lane >= off) x += t;
  }
  if (lane == 63) wsum[wid] = x;
  __syncthreads();
  if (tid < 16){
    int s = wsum[tid];
    int y = s;
    #pragma unroll
    for (int off = 1; off < 16; off <<= 1){
      int t = __shfl_up(y, off);
      if (tid >= off) y += t;
    }
    wsum[tid] = y - s;
  }
  __syncthreads();
  if (idx < NN){
    int incl = part[b] + wsum[wid] + x;
    rowptr[idx+1] = incl;
    cursor[idx]   = incl - v;
  }
  if (idx == 0) rowptr[0] = 0;
}

__global__ void k_fill(const int* __restrict__ es, const int* __restrict__ ed,
                       int* __restrict__ cursor, int* __restrict__ csr){
  int e = blockIdx.x*256 + threadIdx.x;
  if (e < NE){
    int pos = atomicAdd(&cursor[ed[e]], 1);
    csr[pos] = es[e];
  }
}

// ---- weight prep ----
__global__ __launch_bounds__(256) void k_wc(const float* __restrict__ W,
        const float* __restrict__ wih, float* __restrict__ Wc){
  int idx = blockIdx.x*256 + threadIdx.x;
  if (idx >= NL*H*450) return;
  int l = idx / (H*450);
  int rem = idx - l*H*450;
  int k = rem / 450;
  int j = rem - k*450;
  const float* Wr = W   + (size_t)l*H*H + (size_t)k*H;
  const float* wr = wih + (size_t)j*H;
  float acc = 0.f;
  for (int t = 0; t < H; ++t) acc = fmaf(Wr[t], wr[t], acc);
  Wc[idx] = acc;
}

__global__ void k_packi(const float* __restrict__ Wc, short* __restrict__ wbi){
  int idx = blockIdx.x*256 + threadIdx.x;    // NL*10*5*3*512
  int li = idx & 511;
  int q = idx >> 9;
  int mat = q % 3; q /= 3;
  int ks = q % 5;  q /= 5;
  int ct = q % 10; int l = q / 10;
  int lane = li >> 3, j = li & 7;
  int k = ks*32 + ((lane >> 4) << 3) + j;
  int col = ct*16 + (lane & 15);
  float v = (k < H && col < H) ? Wc[(size_t)l*H*450 + (size_t)k*450 + mat*H + col] : 0.f;
  wbi[idx] = (short)f2bf(v);
}

__global__ void k_packh(const float* __restrict__ whh, short* __restrict__ wbh){
  int idx = blockIdx.x*256 + threadIdx.x;    // 10*5*3*512
  int li = idx & 511;
  int q = idx >> 9;
  int mat = q % 3; q /= 3;
  int ks = q % 5;  int ct = q / 5;
  int lane = li >> 3, j = li & 7;
  int k = ks*32 + ((lane >> 4) << 3) + j;
  int col = ct*16 + (lane & 15);
  float v = (k < H && col < H) ? whh[(size_t)(mat*H + col)*H + k] : 0.f;
  wbh[idx] = (short)f2bf(v);
}

__global__ void k_packg(const float* __restrict__ gw1, short* __restrict__ gw1b){
  int idx = blockIdx.x*256 + threadIdx.x;    // 13*5*512
  int li = idx & 511;
  int q = idx >> 9;
  int ks = q % 5;  int ct = q / 5;
  int lane = li >> 3, j = li & 7;
  int k = ks*32 + ((lane >> 4) << 3) + j;
  int col = ct*16 + (lane & 15);
  float v = (k < H && col < GH) ? gw1[(size_t)k*GH + col] : 0.f;
  gw1b[idx] = (short)f2bf(v);
}

__global__ void k_cvt(const float* __restrict__ x, short* __restrict__ hb){
  int idx = blockIdx.x*256 + threadIdx.x;    // NN*80
  if (idx >= NN*80) return;
  int n = idx / 80, c2 = idx - n*80;
  int c = c2*2;
  float lo = (c   < H) ? x[(size_t)n*H + c]   : 0.f;
  float hi = (c+1 < H) ? x[(size_t)n*H + c+1] : 0.f;
  ((u32*)hb)[idx] = (u32)f2bf(lo) | ((u32)f2bf(hi) << 16);
}

// ---- fused gather + GRU via MFMA; hbc read-only, hbn written ----
__global__ __launch_bounds__(512) void k_gru(
    const short* __restrict__ hbc, short* __restrict__ hbn,
    const int* __restrict__ rowptr, const int* __restrict__ csr,
    const short* __restrict__ wbi_l, const short* __restrict__ wbh,
    const float* __restrict__ bih, const float* __restrict__ bhh){
  __shared__ short sA[64*LS];
  __shared__ short sH[64*LS];
  const int tid = threadIdx.x;
  const int w = tid >> 6, lane = tid & 63;
  const int l16 = lane & 15, g = lane >> 4, g8 = g*8;
  const bool ext = lane < 16;
  const u32* h32 = (const u32*)hbc;
  u32* sA32 = (u32*)sA;
  u32* sH32 = (u32*)sH;

  for (int chunk = blockIdx.x; chunk < CHN; chunk += gridDim.x){
    __syncthreads();
    const int row0 = chunk*64;

    // ---- phase A: gather agg rows + copy own h rows into LDS ----
    for (int p = 0; p < 4; ++p){
      const int r0 = w*8 + p*2, r1 = r0 + 1;
      const int n0 = row0 + r0, n1 = row0 + r1;
      const bool v0 = n0 < NN, v1 = n1 < NN;
      float x00=0.f,x01=0.f,y00=0.f,y01=0.f;
      float x10=0.f,x11=0.f,y10=0.f,y11=0.f;
      u32 hv0=0u, hu0=0u, hv1=0u, hu1=0u;
      int b0=0,e0=0,b1=0,e1=0;
      if (v0){ b0 = rowptr[n0]; e0 = rowptr[n0+1];
               hv0 = h32[(size_t)n0*80 + lane]; if (ext) hu0 = h32[(size_t)n0*80 + 64 + lane]; }
      if (v1){ b1 = rowptr[n1]; e1 = rowptr[n1+1];
               hv1 = h32[(size_t)n1*80 + lane]; if (ext) hu1 = h32[(size_t)n1*80 + 64 + lane]; }
      const int d0 = e0 - b0, d1 = e1 - b1;
      const int m = d0 < d1 ? d0 : d1;
      #pragma unroll 2
      for (int i = 0; i < m; ++i){
        const u32* ra = h32 + (size_t)csr[b0+i]*80;
        const u32* rb = h32 + (size_t)csr[b1+i]*80;
        u32 va = ra[lane], vb = rb[lane];
        u32 ua=0u, ub=0u;
        if (ext){ ua = ra[64+lane]; ub = rb[64+lane]; }
        x00 += bf2f(va & 0xffffu); x01 += bf2f(va >> 16);
        x10 += bf2f(vb & 0xffffu); x11 += bf2f(vb >> 16);
        if (ext){
          y00 += bf2f(ua & 0xffffu); y01 += bf2f(ua >> 16);
          y10 += bf2f(ub & 0xffffu); y11 += bf2f(ub >> 16);
        }
      }
      #pragma unroll 2
      for (int i = m; i < d0; ++i){
        const u32* ra = h32 + (size_t)csr[b0+i]*80;
        u32 va = ra[lane];
        x00 += bf2f(va & 0xffffu); x01 += bf2f(va >> 16);
        if (ext){ u32 ua = ra[64+lane]; y00 += bf2f(ua & 0xffffu); y01 += bf2f(ua >> 16); }
      }
      #pragma unroll 2
      for (int i = m; i < d1; ++i){
        const u32* rb = h32 + (size_t)csr[b1+i]*80;
        u32 vb = rb[lane];
        x10 += bf2f(vb & 0xffffu); x11 += bf2f(vb >> 16);
        if (ext){ u32 ub = rb[64+lane]; y10 += bf2f(ub & 0xffffu); y11 += bf2f(ub >> 16); }
      }
      sA32[r0*84 + lane] = pack2(x00, x01);
      sA32[r1*84 + lane] = pack2(x10, x11);
      sH32[r0*84 + lane] = hv0;
      sH32[r1*84 + lane] = hv1;
      if (ext){
        sA32[r0*84 + 64 + lane] = pack2(y00, y01);
        sA32[r1*84 + 64 + lane] = pack2(y10, y11);
        sH32[r0*84 + 64 + lane] = hu0;
        sH32[r1*84 + 64 + lane] = hu1;
      }
    }
    __syncthreads();

    // ---- phase B: MFMA + GRU epilogue ----
    int curct = -1;
    bf16x8 B0[5],B1[5],B2[5],B3[5],B4[5],B5[5];
    float bir=0,biz=0,bin_=0,bhr=0,bhz=0,bhn=0;
    int col = 0; bool cv = false;
    for (int t = w*5; t < w*5 + 5; ++t){
      const int ct = t >> 2, rt = t & 3;
      if (ct != curct){
        curct = ct;
        const short* pi = wbi_l + (size_t)ct*(5*3*512) + lane*8;
        const short* ph = wbh   + (size_t)ct*(5*3*512) + lane*8;
        #pragma unroll
        for (int ks = 0; ks < 5; ++ks){
          B0[ks] = *(const bf16x8*)&pi[(ks*3+0)*512];
          B1[ks] = *(const bf16x8*)&pi[(ks*3+1)*512];
          B2[ks] = *(const bf16x8*)&pi[(ks*3+2)*512];
          B3[ks] = *(const bf16x8*)&ph[(ks*3+0)*512];
          B4[ks] = *(const bf16x8*)&ph[(ks*3+1)*512];
          B5[ks] = *(const bf16x8*)&ph[(ks*3+2)*512];
        }
        col = ct*16 + l16;
        cv = col < H;
        bir = cv ? bih[col] : 0.f;  biz = cv ? bih[H+col] : 0.f;  bin_ = cv ? bih[2*H+col] : 0.f;
        bhr = cv ? bhh[col] : 0.f;  bhz = cv ? bhh[H+col] : 0.f;  bhn  = cv ? bhh[2*H+col] : 0.f;
      }
      f32x4 a0={0,0,0,0},a1={0,0,0,0},a2={0,0,0,0},a3={0,0,0,0},a4={0,0,0,0},a5={0,0,0,0};
      const int lr = rt*16 + l16;
      #pragma unroll
      for (int ks = 0; ks < 5; ++ks){
        bf16x8 aA = *(const bf16x8*)&sA[lr*LS + ks*32 + g8];
        bf16x8 aH = *(const bf16x8*)&sH[lr*LS + ks*32 + g8];
        a0 = __builtin_amdgcn_mfma_f32_16x16x32_bf16(aA, B0[ks], a0, 0,0,0);
        a1 = __builtin_amdgcn_mfma_f32_16x16x32_bf16(aA, B1[ks], a1, 0,0,0);
        a2 = __builtin_amdgcn_mfma_f32_16x16x32_bf16(aA, B2[ks], a2, 0,0,0);
        a3 = __builtin_amdgcn_mfma_f32_16x16x32_bf16(aH, B3[ks], a3, 0,0,0);
        a4 = __builtin_amdgcn_mfma_f32_16x16x32_bf16(aH, B4[ks], a4, 0,0,0);
        a5 = __builtin_amdgcn_mfma_f32_16x16x32_bf16(aH, B5[ks], a5, 0,0,0);
      }
      if (cv){
        #pragma unroll
        for (int r = 0; r < 4; ++r){
          int lrow = rt*16 + g*4 + r;
          int grow = row0 + lrow;
          if (grow < NN){
            float rr = fast_sig(a0[r]+bir + a3[r]+bhr);
            float zz = fast_sig(a1[r]+biz + a4[r]+bhz);
            float nn = fast_tanh(a2[r]+bin_ + rr*(a5[r]+bhn));
            float hold = bf2f((u32)(u16)sH[lrow*LS + col]);
            float hnew = (1.f-zz)*nn + zz*hold;
            hbn[(size_t)grow*HS + col] = (short)f2bf(hnew);
          }
        }
      }
    }
  }
}

// gate_pre via MFMA
__global__ __launch_bounds__(256) void k_gatepre(const short* __restrict__ hb,
      const short* __restrict__ gw1b, const float* __restrict__ gb1,
      const float* __restrict__ gw2, const float* __restrict__ gb2,
      float* __restrict__ gbuf){
  __shared__ short sh[64*LS];
  __shared__ float part[4][4][4][4];
  const int tid = threadIdx.x;
  const int w = tid >> 6, lane = tid & 63;
  const int l16 = lane & 15, g = lane >> 4, g8 = g*8;
  const int chunk = blockIdx.x, row0 = chunk*64;

  for (int i = tid; i < 64*20; i += 256){
    int r = i/20, c = i - r*20;
    int gr = row0 + r;
    bf16x8 v = {0,0,0,0,0,0,0,0};
    if (gr < NN) v = *(const bf16x8*)&hb[(size_t)gr*HS + c*8];
    *(bf16x8*)&sh[r*LS + c*8] = v;
  }
  __syncthreads();

  float acc[4][4];
  #pragma unroll
  for (int rt=0; rt<4; ++rt){
    #pragma unroll
    for (int r=0; r<4; ++r) acc[rt][r] = 0.f;
  }
  for (int ct = w; ct < 13; ct += 4){
    bf16x8 B[5];
    const short* p = gw1b + (size_t)(ct*5)*512 + lane*8;
    #pragma unroll
    for (int ks = 0; ks < 5; ++ks) B[ks] = *(const bf16x8*)&p[ks*512];
    int col = ct*16 + l16;
    bool cv = col < GH;
    float g2 = cv ? gw2[col] : 0.f;
    float b1 = cv ? gb1[col] : 0.f;
    #pragma unroll
    for (int rt = 0; rt < 4; ++rt){
      f32x4 d = {0,0,0,0};
      #pragma unroll
      for (int ks = 0; ks < 5; ++ks){
        bf16x8 aH = *(const bf16x8*)&sh[(rt*16 + l16)*LS + ks*32 + g8];
        d = __builtin_amdgcn_mfma_f32_16x16x32_bf16(aH, B[ks], d, 0,0,0);
      }
      if (cv){
        #pragma unroll
        for (int r = 0; r < 4; ++r) acc[rt][r] += fast_tanh(d[r] + b1) * g2;
      }
    }
  }
  #pragma unroll
  for (int rt = 0; rt < 4; ++rt){
    #pragma unroll
    for (int r = 0; r < 4; ++r){
      float v = acc[rt][r];
      v += __shfl_xor(v, 1); v += __shfl_xor(v, 2);
      v += __shfl_xor(v, 4); v += __shfl_xor(v, 8);
      if (l16 == 0) part[w][rt][g][r] = v;
    }
  }
  __syncthreads();
  if (tid < 64){
    int rt = tid >> 4, gg = (tid >> 2) & 3, r = tid & 3;
    int grow = row0 + tid;
    if (grow < NN)
      gbuf[grow] = part[0][rt][gg][r] + part[1][rt][gg][r]
                 + part[2][rt][gg][r] + part[3][rt][gg][r] + gb2[0];
  }
}

// per-graph segment softmax + weighted sum (bf16 h)
__global__ __launch_bounds__(256) void k_readout(float* __restrict__ gatebuf,
    const short* __restrict__ hb, const int* __restrict__ batch,
    float* __restrict__ out, float* __restrict__ gate_out){
  const int g = blockIdx.x;
  const int tid = threadIdx.x;
  int lo=0, hi=NN;
  while (lo<hi){ int mid=(lo+hi)>>1; if (batch[mid] < g) lo=mid+1; else hi=mid; }
  const int start = lo;
  hi = NN;
  while (lo<hi){ int mid=(lo+hi)>>1; if (batch[mid] < g+1) lo=mid+1; else hi=mid; }
  const int end = lo;

  __shared__ float red[256];
  __shared__ float s_max, s_inv;
  float mx = -INFINITY;
  for (int n = start+tid; n < end; n += 256) mx = fmaxf(mx, gatebuf[n]);
  red[tid]=mx; __syncthreads();
  for (int s=128; s>=1; s>>=1){ if (tid<s) red[tid]=fmaxf(red[tid],red[tid+s]); __syncthreads(); }
  if (tid==0) s_max = red[0];
  __syncthreads();
  const float gmax = s_max;
  float sum = 0.f;
  for (int n = start+tid; n < end; n += 256){
    float e = expf(gatebuf[n]-gmax);
    gatebuf[n] = e;
    sum += e;
  }
  red[tid]=sum; __syncthreads();
  for (int s=128; s>=1; s>>=1){ if (tid<s) red[tid]+=red[tid+s]; __syncthreads(); }
  if (tid==0) s_inv = 1.0f/(red[0] + 1e-16f);
  __syncthreads();
  const float inv = s_inv;
  for (int n = start+tid; n < end; n += 256) gate_out[n] = gatebuf[n]*inv;
  if (tid < 80){
    const u32* h32 = (const u32*)hb;
    float acc0 = 0.f, acc1 = 0.f;
    for (int n = start; n < end; ++n){
      u32 v = h32[(size_t)n*80 + tid];
      float gv = gatebuf[n];
      acc0 = fmaf(gv, bf2f(v & 0xffffu), acc0);
      acc1 = fmaf(gv, bf2f(v >> 16),     acc1);
    }
    int c0 = 2*tid, c1 = 2*tid + 1;
    if (c0 < H) out[g*H + c0] = acc0*inv;
    if (c1 < H) out[g*H + c1] = acc1*inv;
  }
}

extern "C" void kernel_launch(void* const* d_in, const int* in_sizes, int n_in,
                              void* d_out, int out_size, void* d_ws, size_t ws_size,
                              hipStream_t stream) {
  (void)in_sizes; (void)n_in; (void)out_size; (void)ws_size;
  const float* x    = (const float*)d_in[0];
  const int*   eidx = (const int*)d_in[1];
  const int*   batch= (const int*)d_in[2];
  const float* W    = (const float*)d_in[3];
  const float* wih  = (const float*)d_in[4];
  const float* whh  = (const float*)d_in[5];
  const float* bih  = (const float*)d_in[6];
  const float* bhh  = (const float*)d_in[7];
  const float* gw1  = (const float*)d_in[8];
  const float* gb1  = (const float*)d_in[9];
  const float* gw2  = (const float*)d_in[10];
  const float* gb2  = (const float*)d_in[11];

  float* out      = (float*)d_out;
  float* gate_out = out + NG*H;

  char* p = (char*)d_ws;
  float* gbuf  = (float*)p;  p += (size_t)NN*4;
  float* Wc    = (float*)p;  p += (size_t)NL*H*450*4;
  short* hb0   = (short*)p;  p += (size_t)NN*HS*2;
  short* hb1   = (short*)p;  p += (size_t)NN*HS*2;
  short* wbi   = (short*)p;  p += (size_t)NL*76800*2;
  short* wbh   = (short*)p;  p += (size_t)76800*2;
  short* gw1b  = (short*)p;  p += (size_t)33280*2;
  int*   cnt   = (int*)p;    p += (size_t)NN*4;
  int*   rowptr= (int*)p;    p += (size_t)(NN+1)*4;
  int*   cursor= (int*)p;    p += (size_t)NN*4;
  int*   csr   = (int*)p;    p += (size_t)NE*4;
  int*   spart = (int*)p;    p += (size_t)SNB*4;

  const int* esrc = eidx;
  const int* edst = eidx + NE;

  hipMemsetAsync(cnt, 0, sizeof(int)*NN, stream);
  k_hist<<<(NE+255)/256, 256, 0, stream>>>(edst, cnt);
  k_scan1<<<SNB, 256, 0, stream>>>(cnt, spart);
  k_scan2<<<1, 64, 0, stream>>>(spart);
  k_scan3<<<SNB, 1024, 0, stream>>>(cnt, spart, rowptr, cursor);
  k_fill<<<(NE+255)/256, 256, 0, stream>>>(esrc, edst, cursor, csr);

  k_wc   <<<(NL*H*450+255)/256, 256, 0, stream>>>(W, wih, Wc);
  k_packi<<<1500, 256, 0, stream>>>(Wc, wbi);
  k_packh<<<300,  256, 0, stream>>>(whh, wbh);
  k_packg<<<130,  256, 0, stream>>>(gw1, gw1b);

  k_cvt<<<(NN*80+255)/256, 256, 0, stream>>>(x, hb0);

  for (int l = 0; l < NL; ++l){
    short* cur  = (l & 1) ? hb1 : hb0;
    short* next = (l & 1) ? hb0 : hb1;
    k_gru<<<768, 512, 0, stream>>>(cur, next, rowptr, csr,
                                   wbi + (size_t)l*76800, wbh, bih, bhh);
  }
  k_gatepre<<<CHN, 256, 0, stream>>>(hb1, gw1b, gb1, gw2, gb2, gbuf);
  k_readout<<<NG, 256, 0, stream>>>(gbuf, hb1, batch, out, gate_out);
}

// Round 6
// 1840.825 us; speedup vs baseline: 1.9303x; 1.9303x over previous
//
#include <hip/hip_runtime.h>
#include <math.h>

#define NN 100000
#define NE 1600000
#define H 150
#define NG 256
#define NL 5
#define GH 200
#define HS 160          // padded bf16 row stride (elements)
#define LS 168          // LDS row stride in bf16 elems
#define CHN 1563        // ceil(NN/64)
#define SNB 98          // ceil(NN/1024)

typedef unsigned short u16;
typedef unsigned int   u32;
typedef __attribute__((ext_vector_type(8))) short bf16x8;
typedef __attribute__((ext_vector_type(4))) float f32x4;

__device__ __forceinline__ float bf2f(u32 lo16){ u32 t = lo16 << 16; return __builtin_bit_cast(float, t); }
__device__ __forceinline__ u16 f2bf(float f){
  u32 u = __builtin_bit_cast(u32, f);
  u += 0x7fffu + ((u >> 16) & 1u);
  return (u16)(u >> 16);
}
__device__ __forceinline__ u32 pack2(float a, float b){ return (u32)f2bf(a) | ((u32)f2bf(b) << 16); }
__device__ __forceinline__ float fast_sig(float x){
  float e = __expf(-x);
  return __builtin_amdgcn_rcpf(1.f + e);
}
__device__ __forceinline__ float fast_tanh(float x){
  float cx = fminf(fmaxf(x, -15.f), 15.f);
  float e = __expf(2.f*cx);
  return (e - 1.f) * __builtin_amdgcn_rcpf(e + 1.f);
}

// ---- CSR build ----
__global__ void k_hist(const int* __restrict__ ed, int* __restrict__ cnt){
  int e = blockIdx.x*256 + threadIdx.x;
  if (e < NE) atomicAdd(&cnt[ed[e]], 1);
}

__global__ __launch_bounds__(256) void k_scan1(const int* __restrict__ cnt, int* __restrict__ part){
  __shared__ int red[256];
  const int b = blockIdx.x, tid = threadIdx.x;
  const int base = b*1024;
  int s = 0;
  #pragma unroll
  for (int i = 0; i < 4; ++i){
    int idx = base + tid + i*256;
    s += (idx < NN) ? cnt[idx] : 0;
  }
  red[tid] = s; __syncthreads();
  for (int st = 128; st >= 1; st >>= 1){
    if (tid < st) red[tid] += red[tid+st];
    __syncthreads();
  }
  if (tid == 0) part[b] = red[0];
}

__global__ void k_scan2(int* __restrict__ part){
  const int t = threadIdx.x;
  int v0 = (2*t   < SNB) ? part[2*t]   : 0;
  int v1 = (2*t+1 < SNB) ? part[2*t+1] : 0;
  int s = v0 + v1, x = s;
  #pragma unroll
  for (int off = 1; off < 64; off <<= 1){
    int tt = __shfl_up(x, off);
    if (t >= off) x += tt;
  }
  int excl = x - s;
  if (2*t   < SNB) part[2*t]   = excl;
  if (2*t+1 < SNB) part[2*t+1] = excl + v0;
}

__global__ __launch_bounds__(1024) void k_scan3(const int* __restrict__ cnt,
        const int* __restrict__ part, int* __restrict__ rowptr, int* __restrict__ cursor){
  __shared__ int wsum[16];
  const int b = blockIdx.x, tid = threadIdx.x;
  const int wid = tid >> 6, lane = tid & 63;
  const int idx = b*1024 + tid;
  int v = (idx < NN) ? cnt[idx] : 0;
  int x = v;
  #pragma unroll
  for (int off = 1; off < 64; off <<= 1){
    int t = __shfl_up(x, off);
    if (lane >= off) x += t;
  }
  if (lane == 63) wsum[wid] = x;
  __syncthreads();
  if (tid < 16){
    int s = wsum[tid];
    int y = s;
    #pragma unroll
    for (int off = 1; off < 16; off <<= 1){
      int t = __shfl_up(y, off);
      if (tid >= off) y += t;
    }
    wsum[tid] = y - s;
  }
  __syncthreads();
  if (idx < NN){
    int incl = part[b] + wsum[wid] + x;
    rowptr[idx+1] = incl;
    cursor[idx]   = incl - v;
  }
  if (idx == 0) rowptr[0] = 0;
}

__global__ void k_fill(const int* __restrict__ es, const int* __restrict__ ed,
                       int* __restrict__ cursor, int* __restrict__ csr){
  int e = blockIdx.x*256 + threadIdx.x;
  if (e < NE){
    int pos = atomicAdd(&cursor[ed[e]], 1);
    csr[pos] = es[e];
  }
}

// ---- weight prep ----
__global__ __launch_bounds__(256) void k_wc(const float* __restrict__ W,
        const float* __restrict__ wih, float* __restrict__ Wc){
  int idx = blockIdx.x*256 + threadIdx.x;
  if (idx >= NL*H*450) return;
  int l = idx / (H*450);
  int rem = idx - l*H*450;
  int k = rem / 450;
  int j = rem - k*450;
  const float* Wr = W   + (size_t)l*H*H + (size_t)k*H;
  const float* wr = wih + (size_t)j*H;
  float acc = 0.f;
  for (int t = 0; t < H; ++t) acc = fmaf(Wr[t], wr[t], acc);
  Wc[idx] = acc;
}

__global__ void k_packi(const float* __restrict__ Wc, short* __restrict__ wbi){
  int idx = blockIdx.x*256 + threadIdx.x;    // NL*10*5*3*512
  int li = idx & 511;
  int q = idx >> 9;
  int mat = q % 3; q /= 3;
  int ks = q % 5;  q /= 5;
  int ct = q % 10; int l = q / 10;
  int lane = li >> 3, j = li & 7;
  int k = ks*32 + ((lane >> 4) << 3) + j;
  int col = ct*16 + (lane & 15);
  float v = (k < H && col < H) ? Wc[(size_t)l*H*450 + (size_t)k*450 + mat*H + col] : 0.f;
  wbi[idx] = (short)f2bf(v);
}

__global__ void k_packh(const float* __restrict__ whh, short* __restrict__ wbh){
  int idx = blockIdx.x*256 + threadIdx.x;    // 10*5*3*512
  int li = idx & 511;
  int q = idx >> 9;
  int mat = q % 3; q /= 3;
  int ks = q % 5;  int ct = q / 5;
  int lane = li >> 3, j = li & 7;
  int k = ks*32 + ((lane >> 4) << 3) + j;
  int col = ct*16 + (lane & 15);
  float v = (k < H && col < H) ? whh[(size_t)(mat*H + col)*H + k] : 0.f;
  wbh[idx] = (short)f2bf(v);
}

__global__ void k_packg(const float* __restrict__ gw1, short* __restrict__ gw1b){
  int idx = blockIdx.x*256 + threadIdx.x;    // 13*5*512
  int li = idx & 511;
  int q = idx >> 9;
  int ks = q % 5;  int ct = q / 5;
  int lane = li >> 3, j = li & 7;
  int k = ks*32 + ((lane >> 4) << 3) + j;
  int col = ct*16 + (lane & 15);
  float v = (k < H && col < GH) ? gw1[(size_t)k*GH + col] : 0.f;
  gw1b[idx] = (short)f2bf(v);
}

__global__ void k_cvt(const float* __restrict__ x, short* __restrict__ hb){
  int idx = blockIdx.x*256 + threadIdx.x;    // NN*80
  if (idx >= NN*80) return;
  int n = idx / 80, c2 = idx - n*80;
  int c = c2*2;
  float lo = (c   < H) ? x[(size_t)n*H + c]   : 0.f;
  float hi = (c+1 < H) ? x[(size_t)n*H + c+1] : 0.f;
  ((u32*)hb)[idx] = (u32)f2bf(lo) | ((u32)f2bf(hi) << 16);
}

// aggb[n] = sum_{e: dst==n} hb[src[e]]  (bf16 in, fp32 accum, bf16 out)
// one wave per node; 25000 blocks -> TLP hides L2/L3 gather latency
__global__ __launch_bounds__(256) void k_gather(const short* __restrict__ hb,
        const int* __restrict__ rowptr, const int* __restrict__ csr,
        short* __restrict__ aggb){
  const int lane = threadIdx.x & 63;
  const int n = blockIdx.x*4 + (threadIdx.x >> 6);
  if (n >= NN) return;
  const int s0 = rowptr[n], s1 = rowptr[n+1];
  const u32* h32 = (const u32*)hb;
  const bool ext = lane < 16;
  float x0=0.f, x1=0.f, y0=0.f, y1=0.f;
  int j = s0;
  for (; j + 3 < s1; j += 4){
    const u32* r0 = h32 + (size_t)csr[j]*80;
    const u32* r1 = h32 + (size_t)csr[j+1]*80;
    const u32* r2 = h32 + (size_t)csr[j+2]*80;
    const u32* r3 = h32 + (size_t)csr[j+3]*80;
    u32 v0 = r0[lane], v1 = r1[lane], v2 = r2[lane], v3 = r3[lane];
    u32 u0=0,u1=0,u2=0,u3=0;
    if (ext){ u0 = r0[64+lane]; u1 = r1[64+lane]; u2 = r2[64+lane]; u3 = r3[64+lane]; }
    x0 += bf2f(v0 & 0xffffu) + bf2f(v1 & 0xffffu) + bf2f(v2 & 0xffffu) + bf2f(v3 & 0xffffu);
    x1 += bf2f(v0 >> 16)     + bf2f(v1 >> 16)     + bf2f(v2 >> 16)     + bf2f(v3 >> 16);
    if (ext){
      y0 += bf2f(u0 & 0xffffu) + bf2f(u1 & 0xffffu) + bf2f(u2 & 0xffffu) + bf2f(u3 & 0xffffu);
      y1 += bf2f(u0 >> 16)     + bf2f(u1 >> 16)     + bf2f(u2 >> 16)     + bf2f(u3 >> 16);
    }
  }
  for (; j < s1; ++j){
    const u32* r0 = h32 + (size_t)csr[j]*80;
    u32 v0 = r0[lane];
    x0 += bf2f(v0 & 0xffffu); x1 += bf2f(v0 >> 16);
    if (ext){
      u32 u0 = r0[64+lane];
      y0 += bf2f(u0 & 0xffffu); y1 += bf2f(u0 >> 16);
    }
  }
  u32* o = (u32*)aggb + (size_t)n*80;
  o[lane] = pack2(x0, x1);
  if (ext) o[64+lane] = pack2(y0, y1);
}

// ---- GRU via MFMA; reads aggb + hbc, writes hbn (bf16 only) ----
__global__ __launch_bounds__(512, 4) void k_gru(
    const short* __restrict__ aggb, const short* __restrict__ hbc,
    short* __restrict__ hbn,
    const short* __restrict__ wbi_l, const short* __restrict__ wbh,
    const float* __restrict__ bih, const float* __restrict__ bhh){
  __shared__ short sA[64*LS];
  __shared__ short sH[64*LS];
  const int tid = threadIdx.x;
  const int w = tid >> 6, lane = tid & 63;
  const int l16 = lane & 15, g = lane >> 4, g8 = g*8;
  const int row0 = blockIdx.x*64;

  for (int i = tid; i < 64*20; i += 512){
    int r = i/20, c = i - r*20;
    int gr = row0 + r;
    bf16x8 va = {0,0,0,0,0,0,0,0}, vh = {0,0,0,0,0,0,0,0};
    if (gr < NN){
      va = *(const bf16x8*)&aggb[(size_t)gr*HS + c*8];
      vh = *(const bf16x8*)&hbc [(size_t)gr*HS + c*8];
    }
    *(bf16x8*)&sA[r*LS + c*8] = va;
    *(bf16x8*)&sH[r*LS + c*8] = vh;
  }
  __syncthreads();

  int curct = -1;
  bf16x8 B0[5],B1[5],B2[5],B3[5],B4[5],B5[5];
  float bir=0,biz=0,bin_=0,bhr=0,bhz=0,bhn=0;
  int col = 0; bool cv = false;
  for (int t = w*5; t < w*5 + 5; ++t){
    const int ct = t >> 2, rt = t & 3;
    if (ct != curct){
      curct = ct;
      const short* pi = wbi_l + (size_t)ct*(5*3*512) + lane*8;
      const short* ph = wbh   + (size_t)ct*(5*3*512) + lane*8;
      #pragma unroll
      for (int ks = 0; ks < 5; ++ks){
        B0[ks] = *(const bf16x8*)&pi[(ks*3+0)*512];
        B1[ks] = *(const bf16x8*)&pi[(ks*3+1)*512];
        B2[ks] = *(const bf16x8*)&pi[(ks*3+2)*512];
        B3[ks] = *(const bf16x8*)&ph[(ks*3+0)*512];
        B4[ks] = *(const bf16x8*)&ph[(ks*3+1)*512];
        B5[ks] = *(const bf16x8*)&ph[(ks*3+2)*512];
      }
      col = ct*16 + l16;
      cv = col < H;
      bir = cv ? bih[col] : 0.f;  biz = cv ? bih[H+col] : 0.f;  bin_ = cv ? bih[2*H+col] : 0.f;
      bhr = cv ? bhh[col] : 0.f;  bhz = cv ? bhh[H+col] : 0.f;  bhn  = cv ? bhh[2*H+col] : 0.f;
    }
    f32x4 a0={0,0,0,0},a1={0,0,0,0},a2={0,0,0,0},a3={0,0,0,0},a4={0,0,0,0},a5={0,0,0,0};
    const int lr = rt*16 + l16;
    #pragma unroll
    for (int ks = 0; ks < 5; ++ks){
      bf16x8 aA = *(const bf16x8*)&sA[lr*LS + ks*32 + g8];
      bf16x8 aH = *(const bf16x8*)&sH[lr*LS + ks*32 + g8];
      a0 = __builtin_amdgcn_mfma_f32_16x16x32_bf16(aA, B0[ks], a0, 0,0,0);
      a1 = __builtin_amdgcn_mfma_f32_16x16x32_bf16(aA, B1[ks], a1, 0,0,0);
      a2 = __builtin_amdgcn_mfma_f32_16x16x32_bf16(aA, B2[ks], a2, 0,0,0);
      a3 = __builtin_amdgcn_mfma_f32_16x16x32_bf16(aH, B3[ks], a3, 0,0,0);
      a4 = __builtin_amdgcn_mfma_f32_16x16x32_bf16(aH, B4[ks], a4, 0,0,0);
      a5 = __builtin_amdgcn_mfma_f32_16x16x32_bf16(aH, B5[ks], a5, 0,0,0);
    }
    if (cv){
      #pragma unroll
      for (int r = 0; r < 4; ++r){
        int lrow = rt*16 + g*4 + r;
        int grow = row0 + lrow;
        if (grow < NN){
          float rr = fast_sig(a0[r]+bir + a3[r]+bhr);
          float zz = fast_sig(a1[r]+biz + a4[r]+bhz);
          float nn = fast_tanh(a2[r]+bin_ + rr*(a5[r]+bhn));
          float hold = bf2f((u32)(u16)sH[lrow*LS + col]);
          float hnew = (1.f-zz)*nn + zz*hold;
          hbn[(size_t)grow*HS + col] = (short)f2bf(hnew);
        }
      }
    }
  }
}

// gate_pre via MFMA
__global__ __launch_bounds__(256) void k_gatepre(const short* __restrict__ hb,
      const short* __restrict__ gw1b, const float* __restrict__ gb1,
      const float* __restrict__ gw2, const float* __restrict__ gb2,
      float* __restrict__ gbuf){
  __shared__ short sh[64*LS];
  __shared__ float part[4][4][4][4];
  const int tid = threadIdx.x;
  const int w = tid >> 6, lane = tid & 63;
  const int l16 = lane & 15, g = lane >> 4, g8 = g*8;
  const int chunk = blockIdx.x, row0 = chunk*64;

  for (int i = tid; i < 64*20; i += 256){
    int r = i/20, c = i - r*20;
    int gr = row0 + r;
    bf16x8 v = {0,0,0,0,0,0,0,0};
    if (gr < NN) v = *(const bf16x8*)&hb[(size_t)gr*HS + c*8];
    *(bf16x8*)&sh[r*LS + c*8] = v;
  }
  __syncthreads();

  float acc[4][4];
  #pragma unroll
  for (int rt=0; rt<4; ++rt){
    #pragma unroll
    for (int r=0; r<4; ++r) acc[rt][r] = 0.f;
  }
  for (int ct = w; ct < 13; ct += 4){
    bf16x8 B[5];
    const short* p = gw1b + (size_t)(ct*5)*512 + lane*8;
    #pragma unroll
    for (int ks = 0; ks < 5; ++ks) B[ks] = *(const bf16x8*)&p[ks*512];
    int col = ct*16 + l16;
    bool cv = col < GH;
    float g2 = cv ? gw2[col] : 0.f;
    float b1 = cv ? gb1[col] : 0.f;
    #pragma unroll
    for (int rt = 0; rt < 4; ++rt){
      f32x4 d = {0,0,0,0};
      #pragma unroll
      for (int ks = 0; ks < 5; ++ks){
        bf16x8 aH = *(const bf16x8*)&sh[(rt*16 + l16)*LS + ks*32 + g8];
        d = __builtin_amdgcn_mfma_f32_16x16x32_bf16(aH, B[ks], d, 0,0,0);
      }
      if (cv){
        #pragma unroll
        for (int r = 0; r < 4; ++r) acc[rt][r] += fast_tanh(d[r] + b1) * g2;
      }
    }
  }
  #pragma unroll
  for (int rt = 0; rt < 4; ++rt){
    #pragma unroll
    for (int r = 0; r < 4; ++r){
      float v = acc[rt][r];
      v += __shfl_xor(v, 1); v += __shfl_xor(v, 2);
      v += __shfl_xor(v, 4); v += __shfl_xor(v, 8);
      if (l16 == 0) part[w][rt][g][r] = v;
    }
  }
  __syncthreads();
  if (tid < 64){
    int rt = tid >> 4, gg = (tid >> 2) & 3, r = tid & 3;
    int grow = row0 + tid;
    if (grow < NN)
      gbuf[grow] = part[0][rt][gg][r] + part[1][rt][gg][r]
                 + part[2][rt][gg][r] + part[3][rt][gg][r] + gb2[0];
  }
}

// per-graph segment softmax + weighted sum (bf16 h)
__global__ __launch_bounds__(256) void k_readout(float* __restrict__ gatebuf,
    const short* __restrict__ hb, const int* __restrict__ batch,
    float* __restrict__ out, float* __restrict__ gate_out){
  const int g = blockIdx.x;
  const int tid = threadIdx.x;
  int lo=0, hi=NN;
  while (lo<hi){ int mid=(lo+hi)>>1; if (batch[mid] < g) lo=mid+1; else hi=mid; }
  const int start = lo;
  hi = NN;
  while (lo<hi){ int mid=(lo+hi)>>1; if (batch[mid] < g+1) lo=mid+1; else hi=mid; }
  const int end = lo;

  __shared__ float red[256];
  __shared__ float s_max, s_inv;
  float mx = -INFINITY;
  for (int n = start+tid; n < end; n += 256) mx = fmaxf(mx, gatebuf[n]);
  red[tid]=mx; __syncthreads();
  for (int s=128; s>=1; s>>=1){ if (tid<s) red[tid]=fmaxf(red[tid],red[tid+s]); __syncthreads(); }
  if (tid==0) s_max = red[0];
  __syncthreads();
  const float gmax = s_max;
  float sum = 0.f;
  for (int n = start+tid; n < end; n += 256){
    float e = expf(gatebuf[n]-gmax);
    gatebuf[n] = e;
    sum += e;
  }
  red[tid]=sum; __syncthreads();
  for (int s=128; s>=1; s>>=1){ if (tid<s) red[tid]+=red[tid+s]; __syncthreads(); }
  if (tid==0) s_inv = 1.0f/(red[0] + 1e-16f);
  __syncthreads();
  const float inv = s_inv;
  for (int n = start+tid; n < end; n += 256) gate_out[n] = gatebuf[n]*inv;
  if (tid < 80){
    const u32* h32 = (const u32*)hb;
    float acc0 = 0.f, acc1 = 0.f;
    for (int n = start; n < end; ++n){
      u32 v = h32[(size_t)n*80 + tid];
      float gv = gatebuf[n];
      acc0 = fmaf(gv, bf2f(v & 0xffffu), acc0);
      acc1 = fmaf(gv, bf2f(v >> 16),     acc1);
    }
    int c0 = 2*tid, c1 = 2*tid + 1;
    if (c0 < H) out[g*H + c0] = acc0*inv;
    if (c1 < H) out[g*H + c1] = acc1*inv;
  }
}

extern "C" void kernel_launch(void* const* d_in, const int* in_sizes, int n_in,
                              void* d_out, int out_size, void* d_ws, size_t ws_size,
                              hipStream_t stream) {
  (void)in_sizes; (void)n_in; (void)out_size; (void)ws_size;
  const float* x    = (const float*)d_in[0];
  const int*   eidx = (const int*)d_in[1];
  const int*   batch= (const int*)d_in[2];
  const float* W    = (const float*)d_in[3];
  const float* wih  = (const float*)d_in[4];
  const float* whh  = (const float*)d_in[5];
  const float* bih  = (const float*)d_in[6];
  const float* bhh  = (const float*)d_in[7];
  const float* gw1  = (const float*)d_in[8];
  const float* gb1  = (const float*)d_in[9];
  const float* gw2  = (const float*)d_in[10];
  const float* gb2  = (const float*)d_in[11];

  float* out      = (float*)d_out;
  float* gate_out = out + NG*H;

  char* p = (char*)d_ws;
  float* gbuf  = (float*)p;  p += (size_t)NN*4;
  float* Wc    = (float*)p;  p += (size_t)NL*H*450*4;
  short* hb0   = (short*)p;  p += (size_t)NN*HS*2;
  short* hb1   = (short*)p;  p += (size_t)NN*HS*2;
  short* aggb  = (short*)p;  p += (size_t)NN*HS*2;
  short* wbi   = (short*)p;  p += (size_t)NL*76800*2;
  short* wbh   = (short*)p;  p += (size_t)76800*2;
  short* gw1b  = (short*)p;  p += (size_t)33280*2;
  int*   cnt   = (int*)p;    p += (size_t)NN*4;
  int*   rowptr= (int*)p;    p += (size_t)(NN+1)*4;
  int*   cursor= (int*)p;    p += (size_t)NN*4;
  int*   csr   = (int*)p;    p += (size_t)NE*4;
  int*   spart = (int*)p;    p += (size_t)SNB*4;

  const int* esrc = eidx;
  const int* edst = eidx + NE;

  hipMemsetAsync(cnt, 0, sizeof(int)*NN, stream);
  k_hist<<<(NE+255)/256, 256, 0, stream>>>(edst, cnt);
  k_scan1<<<SNB, 256, 0, stream>>>(cnt, spart);
  k_scan2<<<1, 64, 0, stream>>>(spart);
  k_scan3<<<SNB, 1024, 0, stream>>>(cnt, spart, rowptr, cursor);
  k_fill<<<(NE+255)/256, 256, 0, stream>>>(esrc, edst, cursor, csr);

  k_wc   <<<(NL*H*450+255)/256, 256, 0, stream>>>(W, wih, Wc);
  k_packi<<<1500, 256, 0, stream>>>(Wc, wbi);
  k_packh<<<300,  256, 0, stream>>>(whh, wbh);
  k_packg<<<130,  256, 0, stream>>>(gw1, gw1b);

  k_cvt<<<(NN*80+255)/256, 256, 0, stream>>>(x, hb0);

  for (int l = 0; l < NL; ++l){
    short* cur  = (l & 1) ? hb1 : hb0;
    short* next = (l & 1) ? hb0 : hb1;
    k_gather<<<NN/4, 256, 0, stream>>>(cur, rowptr, csr, aggb);
    k_gru<<<CHN, 512, 0, stream>>>(aggb, cur, next,
                                   wbi + (size_t)l*76800, wbh, bih, bhh);
  }
  k_gatepre<<<CHN, 256, 0, stream>>>(hb1, gw1b, gb1, gw2, gb2, gbuf);
  k_readout<<<NG, 256, 0, stream>>>(gbuf, hb1, batch, out, gate_out);
}

// Round 7
// 1306.606 us; speedup vs baseline: 2.7196x; 1.4089x over previous
//
#include <hip/hip_runtime.h>
#include <math.h>

#define NN 100000
#define NE 1600000
#define H 150
#define NG 256
#define NL 5
#define GH 200
#define HS 160          // padded bf16 row stride (elements)
#define LS 168          // LDS row stride in bf16 elems
#define CHN 1563        // ceil(NN/64)
#define SNB 98          // ceil(NN/1024)

typedef unsigned short u16;
typedef unsigned int   u32;
typedef __attribute__((ext_vector_type(8))) short bf16x8;
typedef __attribute__((ext_vector_type(4))) float f32x4;

__device__ __forceinline__ float bf2f(u32 lo16){ u32 t = lo16 << 16; return __builtin_bit_cast(float, t); }
__device__ __forceinline__ u16 f2bf(float f){
  u32 u = __builtin_bit_cast(u32, f);
  u += 0x7fffu + ((u >> 16) & 1u);
  return (u16)(u >> 16);
}
__device__ __forceinline__ u32 pack2(float a, float b){ return (u32)f2bf(a) | ((u32)f2bf(b) << 16); }
__device__ __forceinline__ float fast_sig(float x){
  float e = __expf(-x);
  return __builtin_amdgcn_rcpf(1.f + e);
}
__device__ __forceinline__ float fast_tanh(float x){
  float cx = fminf(fmaxf(x, -15.f), 15.f);
  float e = __expf(2.f*cx);
  return (e - 1.f) * __builtin_amdgcn_rcpf(e + 1.f);
}

// ---- CSR build ----
__global__ void k_hist(const int* __restrict__ ed, int* __restrict__ cnt){
  int e = blockIdx.x*256 + threadIdx.x;
  if (e < NE) atomicAdd(&cnt[ed[e]], 1);
}

__global__ __launch_bounds__(256) void k_scan1(const int* __restrict__ cnt, int* __restrict__ part){
  __shared__ int red[256];
  const int b = blockIdx.x, tid = threadIdx.x;
  const int base = b*1024;
  int s = 0;
  #pragma unroll
  for (int i = 0; i < 4; ++i){
    int idx = base + tid + i*256;
    s += (idx < NN) ? cnt[idx] : 0;
  }
  red[tid] = s; __syncthreads();
  for (int st = 128; st >= 1; st >>= 1){
    if (tid < st) red[tid] += red[tid+st];
    __syncthreads();
  }
  if (tid == 0) part[b] = red[0];
}

__global__ void k_scan2(int* __restrict__ part){
  const int t = threadIdx.x;
  int v0 = (2*t   < SNB) ? part[2*t]   : 0;
  int v1 = (2*t+1 < SNB) ? part[2*t+1] : 0;
  int s = v0 + v1, x = s;
  #pragma unroll
  for (int off = 1; off < 64; off <<= 1){
    int tt = __shfl_up(x, off);
    if (t >= off) x += tt;
  }
  int excl = x - s;
  if (2*t   < SNB) part[2*t]   = excl;
  if (2*t+1 < SNB) part[2*t+1] = excl + v0;
}

__global__ __launch_bounds__(1024) void k_scan3(const int* __restrict__ cnt,
        const int* __restrict__ part, int* __restrict__ rowptr, int* __restrict__ cursor){
  __shared__ int wsum[16];
  const int b = blockIdx.x, tid = threadIdx.x;
  const int wid = tid >> 6, lane = tid & 63;
  const int idx = b*1024 + tid;
  int v = (idx < NN) ? cnt[idx] : 0;
  int x = v;
  #pragma unroll
  for (int off = 1; off < 64; off <<= 1){
    int t = __shfl_up(x, off);
    if (lane >= off) x += t;
  }
  if (lane == 63) wsum[wid] = x;
  __syncthreads();
  if (tid < 16){
    int s = wsum[tid];
    int y = s;
    #pragma unroll
    for (int off = 1; off < 16; off <<= 1){
      int t = __shfl_up(y, off);
      if (tid >= off) y += t;
    }
    wsum[tid] = y - s;
  }
  __syncthreads();
  if (idx < NN){
    int incl = part[b] + wsum[wid] + x;
    rowptr[idx+1] = incl;
    cursor[idx]   = incl - v;
  }
  if (idx == 0) rowptr[0] = 0;
}

__global__ void k_fill(const int* __restrict__ es, const int* __restrict__ ed,
                       int* __restrict__ cursor, int* __restrict__ csr){
  int e = blockIdx.x*256 + threadIdx.x;
  if (e < NE){
    int pos = atomicAdd(&cursor[ed[e]], 1);
    csr[pos] = es[e];
  }
}

// ---- weight prep ----
__global__ __launch_bounds__(256) void k_wc(const float* __restrict__ W,
        const float* __restrict__ wih, float* __restrict__ Wc){
  int idx = blockIdx.x*256 + threadIdx.x;
  if (idx >= NL*H*450) return;
  int l = idx / (H*450);
  int rem = idx - l*H*450;
  int k = rem / 450;
  int j = rem - k*450;
  const float* Wr = W   + (size_t)l*H*H + (size_t)k*H;
  const float* wr = wih + (size_t)j*H;
  float acc = 0.f;
  for (int t = 0; t < H; ++t) acc = fmaf(Wr[t], wr[t], acc);
  Wc[idx] = acc;
}

__global__ void k_packi(const float* __restrict__ Wc, short* __restrict__ wbi){
  int idx = blockIdx.x*256 + threadIdx.x;    // NL*10*5*3*512
  int li = idx & 511;
  int q = idx >> 9;
  int mat = q % 3; q /= 3;
  int ks = q % 5;  q /= 5;
  int ct = q % 10; int l = q / 10;
  int lane = li >> 3, j = li & 7;
  int k = ks*32 + ((lane >> 4) << 3) + j;
  int col = ct*16 + (lane & 15);
  float v = (k < H && col < H) ? Wc[(size_t)l*H*450 + (size_t)k*450 + mat*H + col] : 0.f;
  wbi[idx] = (short)f2bf(v);
}

__global__ void k_packh(const float* __restrict__ whh, short* __restrict__ wbh){
  int idx = blockIdx.x*256 + threadIdx.x;    // 10*5*3*512
  int li = idx & 511;
  int q = idx >> 9;
  int mat = q % 3; q /= 3;
  int ks = q % 5;  int ct = q / 5;
  int lane = li >> 3, j = li & 7;
  int k = ks*32 + ((lane >> 4) << 3) + j;
  int col = ct*16 + (lane & 15);
  float v = (k < H && col < H) ? whh[(size_t)(mat*H + col)*H + k] : 0.f;
  wbh[idx] = (short)f2bf(v);
}

__global__ void k_packg(const float* __restrict__ gw1, short* __restrict__ gw1b){
  int idx = blockIdx.x*256 + threadIdx.x;    // 13*5*512
  int li = idx & 511;
  int q = idx >> 9;
  int ks = q % 5;  int ct = q / 5;
  int lane = li >> 3, j = li & 7;
  int k = ks*32 + ((lane >> 4) << 3) + j;
  int col = ct*16 + (lane & 15);
  float v = (k < H && col < GH) ? gw1[(size_t)k*GH + col] : 0.f;
  gw1b[idx] = (short)f2bf(v);
}

__global__ void k_cvt(const float* __restrict__ x, short* __restrict__ hb){
  int idx = blockIdx.x*256 + threadIdx.x;    // NN*80
  if (idx >= NN*80) return;
  int n = idx / 80, c2 = idx - n*80;
  int c = c2*2;
  float lo = (c   < H) ? x[(size_t)n*H + c]   : 0.f;
  float hi = (c+1 < H) ? x[(size_t)n*H + c+1] : 0.f;
  ((u32*)hb)[idx] = (u32)f2bf(lo) | ((u32)f2bf(hi) << 16);
}

// aggb[n] = sum_{e: dst==n} hb[src[e]]  (bf16 in, fp32 accum, bf16 out)
__global__ __launch_bounds__(256) void k_gather(const short* __restrict__ hb,
        const int* __restrict__ rowptr, const int* __restrict__ csr,
        short* __restrict__ aggb){
  const int lane = threadIdx.x & 63;
  const int n = blockIdx.x*4 + (threadIdx.x >> 6);
  if (n >= NN) return;
  const int s0 = rowptr[n], s1 = rowptr[n+1];
  const u32* h32 = (const u32*)hb;
  const bool ext = lane < 16;
  float x0=0.f, x1=0.f, y0=0.f, y1=0.f;
  int j = s0;
  for (; j + 3 < s1; j += 4){
    const u32* r0 = h32 + (size_t)csr[j]*80;
    const u32* r1 = h32 + (size_t)csr[j+1]*80;
    const u32* r2 = h32 + (size_t)csr[j+2]*80;
    const u32* r3 = h32 + (size_t)csr[j+3]*80;
    u32 v0 = r0[lane], v1 = r1[lane], v2 = r2[lane], v3 = r3[lane];
    u32 u0=0,u1=0,u2=0,u3=0;
    if (ext){ u0 = r0[64+lane]; u1 = r1[64+lane]; u2 = r2[64+lane]; u3 = r3[64+lane]; }
    x0 += bf2f(v0 & 0xffffu) + bf2f(v1 & 0xffffu) + bf2f(v2 & 0xffffu) + bf2f(v3 & 0xffffu);
    x1 += bf2f(v0 >> 16)     + bf2f(v1 >> 16)     + bf2f(v2 >> 16)     + bf2f(v3 >> 16);
    if (ext){
      y0 += bf2f(u0 & 0xffffu) + bf2f(u1 & 0xffffu) + bf2f(u2 & 0xffffu) + bf2f(u3 & 0xffffu);
      y1 += bf2f(u0 >> 16)     + bf2f(u1 >> 16)     + bf2f(u2 >> 16)     + bf2f(u3 >> 16);
    }
  }
  for (; j < s1; ++j){
    const u32* r0 = h32 + (size_t)csr[j]*80;
    u32 v0 = r0[lane];
    x0 += bf2f(v0 & 0xffffu); x1 += bf2f(v0 >> 16);
    if (ext){
      u32 u0 = r0[64+lane];
      y0 += bf2f(u0 & 0xffffu); y1 += bf2f(u0 >> 16);
    }
  }
  u32* o = (u32*)aggb + (size_t)n*80;
  o[lane] = pack2(x0, x1);
  if (ext) o[64+lane] = pack2(y0, y1);
}

// ---- GRU via MFMA; B-fragments streamed through LDS (30 KB per ct) ----
// 256 threads = 4 waves; wave w owns row-tile rt=w (16 rows); ct loop 0..9.
__global__ __launch_bounds__(256, 2) void k_gru(
    const short* __restrict__ aggb, const short* __restrict__ hbc,
    short* __restrict__ hbn,
    const short* __restrict__ wbi_l, const short* __restrict__ wbh,
    const float* __restrict__ bih, const float* __restrict__ bhh){
  __shared__ short sA[64*LS];
  __shared__ short sH[64*LS];
  __shared__ short sB[30*512];   // [slot 0..14: gi (ks*3+mat)][slot 15..29: gh]
  const int tid = threadIdx.x;
  const int w = tid >> 6, lane = tid & 63;
  const int l16 = lane & 15, g = lane >> 4, g8 = g*8;
  const int row0 = blockIdx.x*64;

  // stage state (64 rows x 20 chunks of 16B)
  for (int i = tid; i < 64*20; i += 256){
    int r = i/20, c = i - r*20;
    int gr = row0 + r;
    bf16x8 va = {0,0,0,0,0,0,0,0}, vh = {0,0,0,0,0,0,0,0};
    if (gr < NN){
      va = *(const bf16x8*)&aggb[(size_t)gr*HS + c*8];
      vh = *(const bf16x8*)&hbc [(size_t)gr*HS + c*8];
    }
    *(bf16x8*)&sA[r*LS + c*8] = va;
    *(bf16x8*)&sH[r*LS + c*8] = vh;
  }

  // B prefetch registers: 1920 16B-units per ct, 256 threads -> 8 units max
  bf16x8 pr[8];
  #pragma unroll
  for (int k2 = 0; k2 < 8; ++k2){
    int u = tid + k2*256;
    if (u < 1920){
      int s = u >> 6, e = u & 63;
      const short* src = (s < 15) ? (wbi_l + s*512 + e*8)
                                  : (wbh  + (s-15)*512 + e*8);
      pr[k2] = *(const bf16x8*)src;
    }
  }

  for (int ct = 0; ct < 10; ++ct){
    __syncthreads();                 // prev compute done reading sB
    #pragma unroll
    for (int k2 = 0; k2 < 8; ++k2){
      int u = tid + k2*256;
      if (u < 1920) *(bf16x8*)&sB[u*8] = pr[k2];
    }
    __syncthreads();                 // sB (and, at ct=0, sA/sH) ready
    if (ct < 9){
      const int cto = (ct+1)*7680;
      #pragma unroll
      for (int k2 = 0; k2 < 8; ++k2){
        int u = tid + k2*256;
        if (u < 1920){
          int s = u >> 6, e = u & 63;
          const short* src = (s < 15) ? (wbi_l + cto + s*512 + e*8)
                                      : (wbh  + cto + (s-15)*512 + e*8);
          pr[k2] = *(const bf16x8*)src;
        }
      }
    }

    const int col = ct*16 + l16;
    const bool cv = col < H;
    float bir = cv ? bih[col] : 0.f, biz = cv ? bih[H+col] : 0.f, bin_ = cv ? bih[2*H+col] : 0.f;
    float bhr = cv ? bhh[col] : 0.f, bhz = cv ? bhh[H+col] : 0.f, bhn  = cv ? bhh[2*H+col] : 0.f;

    f32x4 a0={0,0,0,0},a1={0,0,0,0},a2={0,0,0,0},a3={0,0,0,0},a4={0,0,0,0},a5={0,0,0,0};
    const int lr = w*16 + l16;
    #pragma unroll
    for (int ks = 0; ks < 5; ++ks){
      bf16x8 aA = *(const bf16x8*)&sA[lr*LS + ks*32 + g8];
      bf16x8 aH = *(const bf16x8*)&sH[lr*LS + ks*32 + g8];
      bf16x8 b0 = *(const bf16x8*)&sB[(ks*3+0)*512 + lane*8];
      bf16x8 b1 = *(const bf16x8*)&sB[(ks*3+1)*512 + lane*8];
      bf16x8 b2 = *(const bf16x8*)&sB[(ks*3+2)*512 + lane*8];
      bf16x8 c0 = *(const bf16x8*)&sB[(15+ks*3+0)*512 + lane*8];
      bf16x8 c1 = *(const bf16x8*)&sB[(15+ks*3+1)*512 + lane*8];
      bf16x8 c2 = *(const bf16x8*)&sB[(15+ks*3+2)*512 + lane*8];
      a0 = __builtin_amdgcn_mfma_f32_16x16x32_bf16(aA, b0, a0, 0,0,0);
      a1 = __builtin_amdgcn_mfma_f32_16x16x32_bf16(aA, b1, a1, 0,0,0);
      a2 = __builtin_amdgcn_mfma_f32_16x16x32_bf16(aA, b2, a2, 0,0,0);
      a3 = __builtin_amdgcn_mfma_f32_16x16x32_bf16(aH, c0, a3, 0,0,0);
      a4 = __builtin_amdgcn_mfma_f32_16x16x32_bf16(aH, c1, a4, 0,0,0);
      a5 = __builtin_amdgcn_mfma_f32_16x16x32_bf16(aH, c2, a5, 0,0,0);
    }
    if (cv){
      #pragma unroll
      for (int r = 0; r < 4; ++r){
        int lrow = w*16 + g*4 + r;
        int grow = row0 + lrow;
        if (grow < NN){
          float rr = fast_sig(a0[r]+bir + a3[r]+bhr);
          float zz = fast_sig(a1[r]+biz + a4[r]+bhz);
          float nn = fast_tanh(a2[r]+bin_ + rr*(a5[r]+bhn));
          float hold = bf2f((u32)(u16)sH[lrow*LS + col]);
          float hnew = (1.f-zz)*nn + zz*hold;
          hbn[(size_t)grow*HS + col] = (short)f2bf(hnew);
        }
      }
    }
  }
}

// gate_pre via MFMA
__global__ __launch_bounds__(256) void k_gatepre(const short* __restrict__ hb,
      const short* __restrict__ gw1b, const float* __restrict__ gb1,
      const float* __restrict__ gw2, const float* __restrict__ gb2,
      float* __restrict__ gbuf){
  __shared__ short sh[64*LS];
  __shared__ float part[4][4][4][4];
  const int tid = threadIdx.x;
  const int w = tid >> 6, lane = tid & 63;
  const int l16 = lane & 15, g = lane >> 4, g8 = g*8;
  const int chunk = blockIdx.x, row0 = chunk*64;

  for (int i = tid; i < 64*20; i += 256){
    int r = i/20, c = i - r*20;
    int gr = row0 + r;
    bf16x8 v = {0,0,0,0,0,0,0,0};
    if (gr < NN) v = *(const bf16x8*)&hb[(size_t)gr*HS + c*8];
    *(bf16x8*)&sh[r*LS + c*8] = v;
  }
  __syncthreads();

  float acc[4][4];
  #pragma unroll
  for (int rt=0; rt<4; ++rt){
    #pragma unroll
    for (int r=0; r<4; ++r) acc[rt][r] = 0.f;
  }
  for (int ct = w; ct < 13; ct += 4){
    bf16x8 B[5];
    const short* p = gw1b + (size_t)(ct*5)*512 + lane*8;
    #pragma unroll
    for (int ks = 0; ks < 5; ++ks) B[ks] = *(const bf16x8*)&p[ks*512];
    int col = ct*16 + l16;
    bool cv = col < GH;
    float g2 = cv ? gw2[col] : 0.f;
    float b1 = cv ? gb1[col] : 0.f;
    #pragma unroll
    for (int rt = 0; rt < 4; ++rt){
      f32x4 d = {0,0,0,0};
      #pragma unroll
      for (int ks = 0; ks < 5; ++ks){
        bf16x8 aH = *(const bf16x8*)&sh[(rt*16 + l16)*LS + ks*32 + g8];
        d = __builtin_amdgcn_mfma_f32_16x16x32_bf16(aH, B[ks], d, 0,0,0);
      }
      if (cv){
        #pragma unroll
        for (int r = 0; r < 4; ++r) acc[rt][r] += fast_tanh(d[r] + b1) * g2;
      }
    }
  }
  #pragma unroll
  for (int rt = 0; rt < 4; ++rt){
    #pragma unroll
    for (int r = 0; r < 4; ++r){
      float v = acc[rt][r];
      v += __shfl_xor(v, 1); v += __shfl_xor(v, 2);
      v += __shfl_xor(v, 4); v += __shfl_xor(v, 8);
      if (l16 == 0) part[w][rt][g][r] = v;
    }
  }
  __syncthreads();
  if (tid < 64){
    int rt = tid >> 4, gg = (tid >> 2) & 3, r = tid & 3;
    int grow = row0 + tid;
    if (grow < NN)
      gbuf[grow] = part[0][rt][gg][r] + part[1][rt][gg][r]
                 + part[2][rt][gg][r] + part[3][rt][gg][r] + gb2[0];
  }
}

// per-graph segment softmax + weighted sum (bf16 h)
__global__ __launch_bounds__(256) void k_readout(float* __restrict__ gatebuf,
    const short* __restrict__ hb, const int* __restrict__ batch,
    float* __restrict__ out, float* __restrict__ gate_out){
  const int g = blockIdx.x;
  const int tid = threadIdx.x;
  int lo=0, hi=NN;
  while (lo<hi){ int mid=(lo+hi)>>1; if (batch[mid] < g) lo=mid+1; else hi=mid; }
  const int start = lo;
  hi = NN;
  while (lo<hi){ int mid=(lo+hi)>>1; if (batch[mid] < g+1) lo=mid+1; else hi=mid; }
  const int end = lo;

  __shared__ float red[256];
  __shared__ float s_max, s_inv;
  float mx = -INFINITY;
  for (int n = start+tid; n < end; n += 256) mx = fmaxf(mx, gatebuf[n]);
  red[tid]=mx; __syncthreads();
  for (int s=128; s>=1; s>>=1){ if (tid<s) red[tid]=fmaxf(red[tid],red[tid+s]); __syncthreads(); }
  if (tid==0) s_max = red[0];
  __syncthreads();
  const float gmax = s_max;
  float sum = 0.f;
  for (int n = start+tid; n < end; n += 256){
    float e = expf(gatebuf[n]-gmax);
    gatebuf[n] = e;
    sum += e;
  }
  red[tid]=sum; __syncthreads();
  for (int s=128; s>=1; s>>=1){ if (tid<s) red[tid]+=red[tid+s]; __syncthreads(); }
  if (tid==0) s_inv = 1.0f/(red[0] + 1e-16f);
  __syncthreads();
  const float inv = s_inv;
  for (int n = start+tid; n < end; n += 256) gate_out[n] = gatebuf[n]*inv;
  if (tid < 80){
    const u32* h32 = (const u32*)hb;
    float acc0 = 0.f, acc1 = 0.f;
    for (int n = start; n < end; ++n){
      u32 v = h32[(size_t)n*80 + tid];
      float gv = gatebuf[n];
      acc0 = fmaf(gv, bf2f(v & 0xffffu), acc0);
      acc1 = fmaf(gv, bf2f(v >> 16),     acc1);
    }
    int c0 = 2*tid, c1 = 2*tid + 1;
    if (c0 < H) out[g*H + c0] = acc0*inv;
    if (c1 < H) out[g*H + c1] = acc1*inv;
  }
}

extern "C" void kernel_launch(void* const* d_in, const int* in_sizes, int n_in,
                              void* d_out, int out_size, void* d_ws, size_t ws_size,
                              hipStream_t stream) {
  (void)in_sizes; (void)n_in; (void)out_size; (void)ws_size;
  const float* x    = (const float*)d_in[0];
  const int*   eidx = (const int*)d_in[1];
  const int*   batch= (const int*)d_in[2];
  const float* W    = (const float*)d_in[3];
  const float* wih  = (const float*)d_in[4];
  const float* whh  = (const float*)d_in[5];
  const float* bih  = (const float*)d_in[6];
  const float* bhh  = (const float*)d_in[7];
  const float* gw1  = (const float*)d_in[8];
  const float* gb1  = (const float*)d_in[9];
  const float* gw2  = (const float*)d_in[10];
  const float* gb2  = (const float*)d_in[11];

  float* out      = (float*)d_out;
  float* gate_out = out + NG*H;

  char* p = (char*)d_ws;
  float* gbuf  = (float*)p;  p += (size_t)NN*4;
  float* Wc    = (float*)p;  p += (size_t)NL*H*450*4;
  short* hb0   = (short*)p;  p += (size_t)NN*HS*2;
  short* hb1   = (short*)p;  p += (size_t)NN*HS*2;
  short* aggb  = (short*)p;  p += (size_t)NN*HS*2;
  short* wbi   = (short*)p;  p += (size_t)NL*76800*2;
  short* wbh   = (short*)p;  p += (size_t)76800*2;
  short* gw1b  = (short*)p;  p += (size_t)33280*2;
  int*   cnt   = (int*)p;    p += (size_t)NN*4;
  int*   rowptr= (int*)p;    p += (size_t)(NN+1)*4;
  int*   cursor= (int*)p;    p += (size_t)NN*4;
  int*   csr   = (int*)p;    p += (size_t)NE*4;
  int*   spart = (int*)p;    p += (size_t)SNB*4;

  const int* esrc = eidx;
  const int* edst = eidx + NE;

  hipMemsetAsync(cnt, 0, sizeof(int)*NN, stream);
  k_hist<<<(NE+255)/256, 256, 0, stream>>>(edst, cnt);
  k_scan1<<<SNB, 256, 0, stream>>>(cnt, spart);
  k_scan2<<<1, 64, 0, stream>>>(spart);
  k_scan3<<<SNB, 1024, 0, stream>>>(cnt, spart, rowptr, cursor);
  k_fill<<<(NE+255)/256, 256, 0, stream>>>(esrc, edst, cursor, csr);

  k_wc   <<<(NL*H*450+255)/256, 256, 0, stream>>>(W, wih, Wc);
  k_packi<<<1500, 256, 0, stream>>>(Wc, wbi);
  k_packh<<<300,  256, 0, stream>>>(whh, wbh);
  k_packg<<<130,  256, 0, stream>>>(gw1, gw1b);

  k_cvt<<<(NN*80+255)/256, 256, 0, stream>>>(x, hb0);

  for (int l = 0; l < NL; ++l){
    short* cur  = (l & 1) ? hb1 : hb0;
    short* next = (l & 1) ? hb0 : hb1;
    k_gather<<<NN/4, 256, 0, stream>>>(cur, rowptr, csr, aggb);
    k_gru<<<CHN, 256, 0, stream>>>(aggb, cur, next,
                                   wbi + (size_t)l*76800, wbh, bih, bhh);
  }
  k_gatepre<<<CHN, 256, 0, stream>>>(hb1, gw1b, gb1, gw2, gb2, gbuf);
  k_readout<<<NG, 256, 0, stream>>>(gbuf, hb1, batch, out, gate_out);
}

// Round 8
// 1259.240 us; speedup vs baseline: 2.8219x; 1.0376x over previous
//
#include <hip/hip_runtime.h>
#include <math.h>

#define NN 100000
#define NE 1600000
#define H 150
#define NG 256
#define NL 5
#define GH 200
#define HS 160          // padded bf16 row stride (elements)
#define LS 168          // LDS row stride in bf16 elems (gatepre)
#define CHN 1563        // ceil(NN/64)
#define CH2 782         // ceil(NN/128)
#define SNB 98          // ceil(NN/1024)

typedef unsigned short u16;
typedef unsigned int   u32;
typedef __attribute__((ext_vector_type(8))) short bf16x8;
typedef __attribute__((ext_vector_type(4))) float f32x4;

__device__ __forceinline__ float bf2f(u32 lo16){ u32 t = lo16 << 16; return __builtin_bit_cast(float, t); }
__device__ __forceinline__ u16 f2bf(float f){
  u32 u = __builtin_bit_cast(u32, f);
  u += 0x7fffu + ((u >> 16) & 1u);
  return (u16)(u >> 16);
}
__device__ __forceinline__ u32 pack2(float a, float b){ return (u32)f2bf(a) | ((u32)f2bf(b) << 16); }
__device__ __forceinline__ float fast_sig(float x){
  float e = __expf(-x);
  return __builtin_amdgcn_rcpf(1.f + e);
}
__device__ __forceinline__ float fast_tanh(float x){
  float cx = fminf(fmaxf(x, -15.f), 15.f);
  float e = __expf(2.f*cx);
  return (e - 1.f) * __builtin_amdgcn_rcpf(e + 1.f);
}

// ---- CSR build ----
__global__ void k_hist(const int* __restrict__ ed, int* __restrict__ cnt){
  int e = blockIdx.x*256 + threadIdx.x;
  if (e < NE) atomicAdd(&cnt[ed[e]], 1);
}

__global__ __launch_bounds__(256) void k_scan1(const int* __restrict__ cnt, int* __restrict__ part){
  __shared__ int red[256];
  const int b = blockIdx.x, tid = threadIdx.x;
  const int base = b*1024;
  int s = 0;
  #pragma unroll
  for (int i = 0; i < 4; ++i){
    int idx = base + tid + i*256;
    s += (idx < NN) ? cnt[idx] : 0;
  }
  red[tid] = s; __syncthreads();
  for (int st = 128; st >= 1; st >>= 1){
    if (tid < st) red[tid] += red[tid+st];
    __syncthreads();
  }
  if (tid == 0) part[b] = red[0];
}

__global__ void k_scan2(int* __restrict__ part){
  const int t = threadIdx.x;
  int v0 = (2*t   < SNB) ? part[2*t]   : 0;
  int v1 = (2*t+1 < SNB) ? part[2*t+1] : 0;
  int s = v0 + v1, x = s;
  #pragma unroll
  for (int off = 1; off < 64; off <<= 1){
    int tt = __shfl_up(x, off);
    if (t >= off) x += tt;
  }
  int excl = x - s;
  if (2*t   < SNB) part[2*t]   = excl;
  if (2*t+1 < SNB) part[2*t+1] = excl + v0;
}

__global__ __launch_bounds__(1024) void k_scan3(const int* __restrict__ cnt,
        const int* __restrict__ part, int* __restrict__ rowptr, int* __restrict__ cursor){
  __shared__ int wsum[16];
  const int b = blockIdx.x, tid = threadIdx.x;
  const int wid = tid >> 6, lane = tid & 63;
  const int idx = b*1024 + tid;
  int v = (idx < NN) ? cnt[idx] : 0;
  int x = v;
  #pragma unroll
  for (int off = 1; off < 64; off <<= 1){
    int t = __shfl_up(x, off);
    if (lane >= off) x += t;
  }
  if (lane == 63) wsum[wid] = x;
  __syncthreads();
  if (tid < 16){
    int s = wsum[tid];
    int y = s;
    #pragma unroll
    for (int off = 1; off < 16; off <<= 1){
      int t = __shfl_up(y, off);
      if (tid >= off) y += t;
    }
    wsum[tid] = y - s;
  }
  __syncthreads();
  if (idx < NN){
    int incl = part[b] + wsum[wid] + x;
    rowptr[idx+1] = incl;
    cursor[idx]   = incl - v;
  }
  if (idx == 0) rowptr[0] = 0;
}

__global__ void k_fill(const int* __restrict__ es, const int* __restrict__ ed,
                       int* __restrict__ cursor, int* __restrict__ csr){
  int e = blockIdx.x*256 + threadIdx.x;
  if (e < NE){
    int pos = atomicAdd(&cursor[ed[e]], 1);
    csr[pos] = es[e];
  }
}

// ---- weight prep ----
__global__ __launch_bounds__(256) void k_wc(const float* __restrict__ W,
        const float* __restrict__ wih, float* __restrict__ Wc){
  int idx = blockIdx.x*256 + threadIdx.x;
  if (idx >= NL*H*450) return;
  int l = idx / (H*450);
  int rem = idx - l*H*450;
  int k = rem / 450;
  int j = rem - k*450;
  const float* Wr = W   + (size_t)l*H*H + (size_t)k*H;
  const float* wr = wih + (size_t)j*H;
  float acc = 0.f;
  for (int t = 0; t < H; ++t) acc = fmaf(Wr[t], wr[t], acc);
  Wc[idx] = acc;
}

__global__ void k_packi(const float* __restrict__ Wc, short* __restrict__ wbi){
  int idx = blockIdx.x*256 + threadIdx.x;    // NL*10*5*3*512
  int li = idx & 511;
  int q = idx >> 9;
  int mat = q % 3; q /= 3;
  int ks = q % 5;  q /= 5;
  int ct = q % 10; int l = q / 10;
  int lane = li >> 3, j = li & 7;
  int k = ks*32 + ((lane >> 4) << 3) + j;
  int col = ct*16 + (lane & 15);
  float v = (k < H && col < H) ? Wc[(size_t)l*H*450 + (size_t)k*450 + mat*H + col] : 0.f;
  wbi[idx] = (short)f2bf(v);
}

__global__ void k_packh(const float* __restrict__ whh, short* __restrict__ wbh){
  int idx = blockIdx.x*256 + threadIdx.x;    // 10*5*3*512
  int li = idx & 511;
  int q = idx >> 9;
  int mat = q % 3; q /= 3;
  int ks = q % 5;  int ct = q / 5;
  int lane = li >> 3, j = li & 7;
  int k = ks*32 + ((lane >> 4) << 3) + j;
  int col = ct*16 + (lane & 15);
  float v = (k < H && col < H) ? whh[(size_t)(mat*H + col)*H + k] : 0.f;
  wbh[idx] = (short)f2bf(v);
}

__global__ void k_packg(const float* __restrict__ gw1, short* __restrict__ gw1b){
  int idx = blockIdx.x*256 + threadIdx.x;    // 13*5*512
  int li = idx & 511;
  int q = idx >> 9;
  int ks = q % 5;  int ct = q / 5;
  int lane = li >> 3, j = li & 7;
  int k = ks*32 + ((lane >> 4) << 3) + j;
  int col = ct*16 + (lane & 15);
  float v = (k < H && col < GH) ? gw1[(size_t)k*GH + col] : 0.f;
  gw1b[idx] = (short)f2bf(v);
}

__global__ void k_cvt(const float* __restrict__ x, short* __restrict__ hb){
  int idx = blockIdx.x*256 + threadIdx.x;    // NN*80
  if (idx >= NN*80) return;
  int n = idx / 80, c2 = idx - n*80;
  int c = c2*2;
  float lo = (c   < H) ? x[(size_t)n*H + c]   : 0.f;
  float hi = (c+1 < H) ? x[(size_t)n*H + c+1] : 0.f;
  ((u32*)hb)[idx] = (u32)f2bf(lo) | ((u32)f2bf(hi) << 16);
}

// aggb[n] = sum_{e: dst==n} hb[src[e]]  (bf16 in, fp32 accum, bf16 out)
__global__ __launch_bounds__(256) void k_gather(const short* __restrict__ hb,
        const int* __restrict__ rowptr, const int* __restrict__ csr,
        short* __restrict__ aggb){
  const int lane = threadIdx.x & 63;
  const int n = blockIdx.x*4 + (threadIdx.x >> 6);
  if (n >= NN) return;
  const int s0 = rowptr[n], s1 = rowptr[n+1];
  const u32* h32 = (const u32*)hb;
  const bool ext = lane < 16;
  float x0=0.f, x1=0.f, y0=0.f, y1=0.f;
  int j = s0;
  for (; j + 7 < s1; j += 8){
    const u32* r0 = h32 + (size_t)csr[j]*80;
    const u32* r1 = h32 + (size_t)csr[j+1]*80;
    const u32* r2 = h32 + (size_t)csr[j+2]*80;
    const u32* r3 = h32 + (size_t)csr[j+3]*80;
    const u32* r4 = h32 + (size_t)csr[j+4]*80;
    const u32* r5 = h32 + (size_t)csr[j+5]*80;
    const u32* r6 = h32 + (size_t)csr[j+6]*80;
    const u32* r7 = h32 + (size_t)csr[j+7]*80;
    u32 v0 = r0[lane], v1 = r1[lane], v2 = r2[lane], v3 = r3[lane];
    u32 v4 = r4[lane], v5 = r5[lane], v6 = r6[lane], v7 = r7[lane];
    u32 u0=0,u1=0,u2=0,u3=0,u4=0,u5=0,u6=0,u7=0;
    if (ext){
      u0 = r0[64+lane]; u1 = r1[64+lane]; u2 = r2[64+lane]; u3 = r3[64+lane];
      u4 = r4[64+lane]; u5 = r5[64+lane]; u6 = r6[64+lane]; u7 = r7[64+lane];
    }
    x0 += bf2f(v0 & 0xffffu) + bf2f(v1 & 0xffffu) + bf2f(v2 & 0xffffu) + bf2f(v3 & 0xffffu)
        + bf2f(v4 & 0xffffu) + bf2f(v5 & 0xffffu) + bf2f(v6 & 0xffffu) + bf2f(v7 & 0xffffu);
    x1 += bf2f(v0 >> 16) + bf2f(v1 >> 16) + bf2f(v2 >> 16) + bf2f(v3 >> 16)
        + bf2f(v4 >> 16) + bf2f(v5 >> 16) + bf2f(v6 >> 16) + bf2f(v7 >> 16);
    if (ext){
      y0 += bf2f(u0 & 0xffffu) + bf2f(u1 & 0xffffu) + bf2f(u2 & 0xffffu) + bf2f(u3 & 0xffffu)
          + bf2f(u4 & 0xffffu) + bf2f(u5 & 0xffffu) + bf2f(u6 & 0xffffu) + bf2f(u7 & 0xffffu);
      y1 += bf2f(u0 >> 16) + bf2f(u1 >> 16) + bf2f(u2 >> 16) + bf2f(u3 >> 16)
          + bf2f(u4 >> 16) + bf2f(u5 >> 16) + bf2f(u6 >> 16) + bf2f(u7 >> 16);
    }
  }
  for (; j < s1; ++j){
    const u32* r0 = h32 + (size_t)csr[j]*80;
    u32 v0 = r0[lane];
    x0 += bf2f(v0 & 0xffffu); x1 += bf2f(v0 >> 16);
    if (ext){
      u32 u0 = r0[64+lane];
      y0 += bf2f(u0 & 0xffffu); y1 += bf2f(u0 >> 16);
    }
  }
  u32* o = (u32*)aggb + (size_t)n*80;
  o[lane] = pack2(x0, x1);
  if (ext) o[64+lane] = pack2(y0, y1);
}

// ---- GRU via MFMA; A/H in registers (global-loaded), B streamed via LDS ----
// 256 threads = 4 waves; block covers 128 rows; wave w owns rows [w*32, w*32+32)
// (2 row-tiles). Each B-fragment read feeds 2 MFMAs -> 0.5 ds_reads per MFMA.
__global__ __launch_bounds__(256, 2) void k_gru(
    const short* __restrict__ aggb, const short* __restrict__ hbc,
    short* __restrict__ hbn,
    const short* __restrict__ wbi_l, const short* __restrict__ wbh,
    const float* __restrict__ bih, const float* __restrict__ bhh){
  __shared__ short sB[30*512];   // slots 0..14: gi (ks*3+mat); 15..29: gh
  const int tid = threadIdx.x;
  const int w = tid >> 6, lane = tid & 63;
  const int l16 = lane & 15, g = lane >> 4, g8 = g*8;
  const int row0 = blockIdx.x*128 + w*32;

  // A-fragments: fA/fH[t][ks], row = row0 + t*16 + l16, elems ks*32+g8..+8
  bf16x8 fA[2][5], fH[2][5];
  #pragma unroll
  for (int t = 0; t < 2; ++t){
    const int r = row0 + t*16 + l16;
    const bool rv = r < NN;
    #pragma unroll
    for (int ks = 0; ks < 5; ++ks){
      bf16x8 va = {0,0,0,0,0,0,0,0}, vh = {0,0,0,0,0,0,0,0};
      if (rv){
        va = *(const bf16x8*)&aggb[(size_t)r*HS + ks*32 + g8];
        vh = *(const bf16x8*)&hbc [(size_t)r*HS + ks*32 + g8];
      }
      fA[t][ks] = va; fH[t][ks] = vh;
    }
  }

  // B prefetch registers: 1920 16B-units per ct, 256 threads -> 8 units max
  bf16x8 pr[8];
  #pragma unroll
  for (int k2 = 0; k2 < 8; ++k2){
    int u = tid + k2*256;
    if (u < 1920){
      int s = u >> 6, e = u & 63;
      const short* src = (s < 15) ? (wbi_l + s*512 + e*8)
                                  : (wbh  + (s-15)*512 + e*8);
      pr[k2] = *(const bf16x8*)src;
    }
  }

  for (int ct = 0; ct < 10; ++ct){
    __syncthreads();                 // prev compute done reading sB
    #pragma unroll
    for (int k2 = 0; k2 < 8; ++k2){
      int u = tid + k2*256;
      if (u < 1920) *(bf16x8*)&sB[u*8] = pr[k2];
    }
    __syncthreads();                 // sB ready
    if (ct < 9){
      const int cto = (ct+1)*7680;
      #pragma unroll
      for (int k2 = 0; k2 < 8; ++k2){
        int u = tid + k2*256;
        if (u < 1920){
          int s = u >> 6, e = u & 63;
          const short* src = (s < 15) ? (wbi_l + cto + s*512 + e*8)
                                      : (wbh  + cto + (s-15)*512 + e*8);
          pr[k2] = *(const bf16x8*)src;
        }
      }
    }

    const int col = ct*16 + l16;
    const bool cv = col < H;
    const float bir = cv ? bih[col] : 0.f, biz = cv ? bih[H+col] : 0.f, bin_ = cv ? bih[2*H+col] : 0.f;
    const float bhr = cv ? bhh[col] : 0.f, bhz = cv ? bhh[H+col] : 0.f, bhn  = cv ? bhh[2*H+col] : 0.f;

    f32x4 ai[2][3], ah[2][3];
    #pragma unroll
    for (int t = 0; t < 2; ++t)
      #pragma unroll
      for (int m = 0; m < 3; ++m){ ai[t][m] = (f32x4){0,0,0,0}; ah[t][m] = (f32x4){0,0,0,0}; }

    #pragma unroll
    for (int ks = 0; ks < 5; ++ks){
      bf16x8 bi0 = *(const bf16x8*)&sB[(ks*3+0)*512 + lane*8];
      bf16x8 bi1 = *(const bf16x8*)&sB[(ks*3+1)*512 + lane*8];
      bf16x8 bi2 = *(const bf16x8*)&sB[(ks*3+2)*512 + lane*8];
      bf16x8 bh0 = *(const bf16x8*)&sB[(15+ks*3+0)*512 + lane*8];
      bf16x8 bh1 = *(const bf16x8*)&sB[(15+ks*3+1)*512 + lane*8];
      bf16x8 bh2 = *(const bf16x8*)&sB[(15+ks*3+2)*512 + lane*8];
      #pragma unroll
      for (int t = 0; t < 2; ++t){
        ai[t][0] = __builtin_amdgcn_mfma_f32_16x16x32_bf16(fA[t][ks], bi0, ai[t][0], 0,0,0);
        ai[t][1] = __builtin_amdgcn_mfma_f32_16x16x32_bf16(fA[t][ks], bi1, ai[t][1], 0,0,0);
        ai[t][2] = __builtin_amdgcn_mfma_f32_16x16x32_bf16(fA[t][ks], bi2, ai[t][2], 0,0,0);
        ah[t][0] = __builtin_amdgcn_mfma_f32_16x16x32_bf16(fH[t][ks], bh0, ah[t][0], 0,0,0);
        ah[t][1] = __builtin_amdgcn_mfma_f32_16x16x32_bf16(fH[t][ks], bh1, ah[t][1], 0,0,0);
        ah[t][2] = __builtin_amdgcn_mfma_f32_16x16x32_bf16(fH[t][ks], bh2, ah[t][2], 0,0,0);
      }
    }

    if (cv){
      #pragma unroll
      for (int t = 0; t < 2; ++t){
        #pragma unroll
        for (int r = 0; r < 4; ++r){
          int grow = row0 + t*16 + g*4 + r;
          if (grow < NN){
            float rr = fast_sig(ai[t][0][r]+bir + ah[t][0][r]+bhr);
            float zz = fast_sig(ai[t][1][r]+biz + ah[t][1][r]+bhz);
            float nn = fast_tanh(ai[t][2][r]+bin_ + rr*(ah[t][2][r]+bhn));
            float hold = bf2f((u32)(u16)hbc[(size_t)grow*HS + col]);
            float hnew = (1.f-zz)*nn + zz*hold;
            hbn[(size_t)grow*HS + col] = (short)f2bf(hnew);
          }
        }
      }
    }
  }
}

// gate_pre via MFMA
__global__ __launch_bounds__(256) void k_gatepre(const short* __restrict__ hb,
      const short* __restrict__ gw1b, const float* __restrict__ gb1,
      const float* __restrict__ gw2, const float* __restrict__ gb2,
      float* __restrict__ gbuf){
  __shared__ short sh[64*LS];
  __shared__ float part[4][4][4][4];
  const int tid = threadIdx.x;
  const int w = tid >> 6, lane = tid & 63;
  const int l16 = lane & 15, g = lane >> 4, g8 = g*8;
  const int chunk = blockIdx.x, row0 = chunk*64;

  for (int i = tid; i < 64*20; i += 256){
    int r = i/20, c = i - r*20;
    int gr = row0 + r;
    bf16x8 v = {0,0,0,0,0,0,0,0};
    if (gr < NN) v = *(const bf16x8*)&hb[(size_t)gr*HS + c*8];
    *(bf16x8*)&sh[r*LS + c*8] = v;
  }
  __syncthreads();

  float acc[4][4];
  #pragma unroll
  for (int rt=0; rt<4; ++rt){
    #pragma unroll
    for (int r=0; r<4; ++r) acc[rt][r] = 0.f;
  }
  for (int ct = w; ct < 13; ct += 4){
    bf16x8 B[5];
    const short* p = gw1b + (size_t)(ct*5)*512 + lane*8;
    #pragma unroll
    for (int ks = 0; ks < 5; ++ks) B[ks] = *(const bf16x8*)&p[ks*512];
    int col = ct*16 + l16;
    bool cv = col < GH;
    float g2 = cv ? gw2[col] : 0.f;
    float b1 = cv ? gb1[col] : 0.f;
    #pragma unroll
    for (int rt = 0; rt < 4; ++rt){
      f32x4 d = {0,0,0,0};
      #pragma unroll
      for (int ks = 0; ks < 5; ++ks){
        bf16x8 aH = *(const bf16x8*)&sh[(rt*16 + l16)*LS + ks*32 + g8];
        d = __builtin_amdgcn_mfma_f32_16x16x32_bf16(aH, B[ks], d, 0,0,0);
      }
      if (cv){
        #pragma unroll
        for (int r = 0; r < 4; ++r) acc[rt][r] += fast_tanh(d[r] + b1) * g2;
      }
    }
  }
  #pragma unroll
  for (int rt = 0; rt < 4; ++rt){
    #pragma unroll
    for (int r = 0; r < 4; ++r){
      float v = acc[rt][r];
      v += __shfl_xor(v, 1); v += __shfl_xor(v, 2);
      v += __shfl_xor(v, 4); v += __shfl_xor(v, 8);
      if (l16 == 0) part[w][rt][g][r] = v;
    }
  }
  __syncthreads();
  if (tid < 64){
    int rt = tid >> 4, gg = (tid >> 2) & 3, r = tid & 3;
    int grow = row0 + tid;
    if (grow < NN)
      gbuf[grow] = part[0][rt][gg][r] + part[1][rt][gg][r]
                 + part[2][rt][gg][r] + part[3][rt][gg][r] + gb2[0];
  }
}

// per-graph segment softmax + weighted sum (bf16 h)
__global__ __launch_bounds__(256) void k_readout(float* __restrict__ gatebuf,
    const short* __restrict__ hb, const int* __restrict__ batch,
    float* __restrict__ out, float* __restrict__ gate_out){
  const int g = blockIdx.x;
  const int tid = threadIdx.x;
  int lo=0, hi=NN;
  while (lo<hi){ int mid=(lo+hi)>>1; if (batch[mid] < g) lo=mid+1; else hi=mid; }
  const int start = lo;
  hi = NN;
  while (lo<hi){ int mid=(lo+hi)>>1; if (batch[mid] < g+1) lo=mid+1; else hi=mid; }
  const int end = lo;

  __shared__ float red[256];
  __shared__ float s_max, s_inv;
  float mx = -INFINITY;
  for (int n = start+tid; n < end; n += 256) mx = fmaxf(mx, gatebuf[n]);
  red[tid]=mx; __syncthreads();
  for (int s=128; s>=1; s>>=1){ if (tid<s) red[tid]=fmaxf(red[tid],red[tid+s]); __syncthreads(); }
  if (tid==0) s_max = red[0];
  __syncthreads();
  const float gmax = s_max;
  float sum = 0.f;
  for (int n = start+tid; n < end; n += 256){
    float e = expf(gatebuf[n]-gmax);
    gatebuf[n] = e;
    sum += e;
  }
  red[tid]=sum; __syncthreads();
  for (int s=128; s>=1; s>>=1){ if (tid<s) red[tid]+=red[tid+s]; __syncthreads(); }
  if (tid==0) s_inv = 1.0f/(red[0] + 1e-16f);
  __syncthreads();
  const float inv = s_inv;
  for (int n = start+tid; n < end; n += 256) gate_out[n] = gatebuf[n]*inv;
  if (tid < 80){
    const u32* h32 = (const u32*)hb;
    float acc0 = 0.f, acc1 = 0.f;
    for (int n = start; n < end; ++n){
      u32 v = h32[(size_t)n*80 + tid];
      float gv = gatebuf[n];
      acc0 = fmaf(gv, bf2f(v & 0xffffu), acc0);
      acc1 = fmaf(gv, bf2f(v >> 16),     acc1);
    }
    int c0 = 2*tid, c1 = 2*tid + 1;
    if (c0 < H) out[g*H + c0] = acc0*inv;
    if (c1 < H) out[g*H + c1] = acc1*inv;
  }
}

extern "C" void kernel_launch(void* const* d_in, const int* in_sizes, int n_in,
                              void* d_out, int out_size, void* d_ws, size_t ws_size,
                              hipStream_t stream) {
  (void)in_sizes; (void)n_in; (void)out_size; (void)ws_size;
  const float* x    = (const float*)d_in[0];
  const int*   eidx = (const int*)d_in[1];
  const int*   batch= (const int*)d_in[2];
  const float* W    = (const float*)d_in[3];
  const float* wih  = (const float*)d_in[4];
  const float* whh  = (const float*)d_in[5];
  const float* bih  = (const float*)d_in[6];
  const float* bhh  = (const float*)d_in[7];
  const float* gw1  = (const float*)d_in[8];
  const float* gb1  = (const float*)d_in[9];
  const float* gw2  = (const float*)d_in[10];
  const float* gb2  = (const float*)d_in[11];

  float* out      = (float*)d_out;
  float* gate_out = out + NG*H;

  char* p = (char*)d_ws;
  float* gbuf  = (float*)p;  p += (size_t)NN*4;
  float* Wc    = (float*)p;  p += (size_t)NL*H*450*4;
  short* hb0   = (short*)p;  p += (size_t)NN*HS*2;
  short* hb1   = (short*)p;  p += (size_t)NN*HS*2;
  short* aggb  = (short*)p;  p += (size_t)NN*HS*2;
  short* wbi   = (short*)p;  p += (size_t)NL*76800*2;
  short* wbh   = (short*)p;  p += (size_t)76800*2;
  short* gw1b  = (short*)p;  p += (size_t)33280*2;
  int*   cnt   = (int*)p;    p += (size_t)NN*4;
  int*   rowptr= (int*)p;    p += (size_t)(NN+1)*4;
  int*   cursor= (int*)p;    p += (size_t)NN*4;
  int*   csr   = (int*)p;    p += (size_t)NE*4;
  int*   spart = (int*)p;    p += (size_t)SNB*4;

  const int* esrc = eidx;
  const int* edst = eidx + NE;

  hipMemsetAsync(cnt, 0, sizeof(int)*NN, stream);
  k_hist<<<(NE+255)/256, 256, 0, stream>>>(edst, cnt);
  k_scan1<<<SNB, 256, 0, stream>>>(cnt, spart);
  k_scan2<<<1, 64, 0, stream>>>(spart);
  k_scan3<<<SNB, 1024, 0, stream>>>(cnt, spart, rowptr, cursor);
  k_fill<<<(NE+255)/256, 256, 0, stream>>>(esrc, edst, cursor, csr);

  k_wc   <<<(NL*H*450+255)/256, 256, 0, stream>>>(W, wih, Wc);
  k_packi<<<1500, 256, 0, stream>>>(Wc, wbi);
  k_packh<<<300,  256, 0, stream>>>(whh, wbh);
  k_packg<<<130,  256, 0, stream>>>(gw1, gw1b);

  k_cvt<<<(NN*80+255)/256, 256, 0, stream>>>(x, hb0);

  for (int l = 0; l < NL; ++l){
    short* cur  = (l & 1) ? hb1 : hb0;
    short* next = (l & 1) ? hb0 : hb1;
    k_gather<<<NN/4, 256, 0, stream>>>(cur, rowptr, csr, aggb);
    k_gru<<<CH2, 256, 0, stream>>>(aggb, cur, next,
                                   wbi + (size_t)l*76800, wbh, bih, bhh);
  }
  k_gatepre<<<CHN, 256, 0, stream>>>(hb1, gw1b, gb1, gw2, gb2, gbuf);
  k_readout<<<NG, 256, 0, stream>>>(gbuf, hb1, batch, out, gate_out);
}

// Round 9
// 1241.086 us; speedup vs baseline: 2.8631x; 1.0146x over previous
//
#include <hip/hip_runtime.h>
#include <math.h>

#define NN 100000
#define NE 1600000
#define H 150
#define NG 256
#define NL 5
#define GH 200
#define HS 160          // padded bf16 row stride (elements)
#define LS 168          // LDS row stride in bf16 elems (gatepre)
#define CHN 1563        // ceil(NN/64)
#define CH2 782         // ceil(NN/128)
#define SNB 98          // ceil(NN/1024)
#define CSRMAX 2304000  // >= NE + 7*NN, divisible by 1024

typedef unsigned short u16;
typedef unsigned int   u32;
typedef __attribute__((ext_vector_type(8))) short bf16x8;
typedef __attribute__((ext_vector_type(4))) float f32x4;

__device__ __forceinline__ float bf2f(u32 lo16){ u32 t = lo16 << 16; return __builtin_bit_cast(float, t); }
__device__ __forceinline__ u16 f2bf(float f){
  u32 u = __builtin_bit_cast(u32, f);
  u += 0x7fffu + ((u >> 16) & 1u);
  return (u16)(u >> 16);
}
__device__ __forceinline__ u32 pack2(float a, float b){ return (u32)f2bf(a) | ((u32)f2bf(b) << 16); }
__device__ __forceinline__ float fast_sig(float x){
  float e = __expf(-x);
  return __builtin_amdgcn_rcpf(1.f + e);
}
__device__ __forceinline__ float fast_tanh(float x){
  float cx = fminf(fmaxf(x, -15.f), 15.f);
  float e = __expf(2.f*cx);
  return (e - 1.f) * __builtin_amdgcn_rcpf(e + 1.f);
}

// ---- CSR build ----
__global__ void k_hist(const int* __restrict__ ed, int* __restrict__ cnt){
  int e = blockIdx.x*256 + threadIdx.x;
  if (e < NE) atomicAdd(&cnt[ed[e]], 1);
}

// padded partial sums: sum of (cnt+7)&~7 per 1024-chunk
__global__ __launch_bounds__(256) void k_scan1(const int* __restrict__ cnt, int* __restrict__ part){
  __shared__ int red[256];
  const int b = blockIdx.x, tid = threadIdx.x;
  const int base = b*1024;
  int s = 0;
  #pragma unroll
  for (int i = 0; i < 4; ++i){
    int idx = base + tid + i*256;
    int v = (idx < NN) ? cnt[idx] : 0;
    s += (v + 7) & ~7;
  }
  red[tid] = s; __syncthreads();
  for (int st = 128; st >= 1; st >>= 1){
    if (tid < st) red[tid] += red[tid+st];
    __syncthreads();
  }
  if (tid == 0) part[b] = red[0];
}

__global__ void k_scan2(int* __restrict__ part){
  const int t = threadIdx.x;
  int v0 = (2*t   < SNB) ? part[2*t]   : 0;
  int v1 = (2*t+1 < SNB) ? part[2*t+1] : 0;
  int s = v0 + v1, x = s;
  #pragma unroll
  for (int off = 1; off < 64; off <<= 1){
    int tt = __shfl_up(x, off);
    if (t >= off) x += tt;
  }
  int excl = x - s;
  if (2*t   < SNB) part[2*t]   = excl;
  if (2*t+1 < SNB) part[2*t+1] = excl + v0;
}

// padded local scan -> rowptr (padded), cursor (padded segment start)
__global__ __launch_bounds__(1024) void k_scan3(const int* __restrict__ cnt,
        const int* __restrict__ part, int* __restrict__ rowptr, int* __restrict__ cursor){
  __shared__ int wsum[16];
  const int b = blockIdx.x, tid = threadIdx.x;
  const int wid = tid >> 6, lane = tid & 63;
  const int idx = b*1024 + tid;
  int c = (idx < NN) ? cnt[idx] : 0;
  int v = (c + 7) & ~7;
  int x = v;
  #pragma unroll
  for (int off = 1; off < 64; off <<= 1){
    int t = __shfl_up(x, off);
    if (lane >= off) x += t;
  }
  if (lane == 63) wsum[wid] = x;
  __syncthreads();
  if (tid < 16){
    int s = wsum[tid];
    int y = s;
    #pragma unroll
    for (int off = 1; off < 16; off <<= 1){
      int t = __shfl_up(y, off);
      if (tid >= off) y += t;
    }
    wsum[tid] = y - s;
  }
  __syncthreads();
  if (idx < NN){
    int incl = part[b] + wsum[wid] + x;
    rowptr[idx+1] = incl;
    cursor[idx]   = incl - v;
  }
  if (idx == 0) rowptr[0] = 0;
}

// prefill csr with dummy index NN (coalesced int4 stores)
__global__ __launch_bounds__(256) void k_pre(int* __restrict__ csr){
  int i = (blockIdx.x*256 + threadIdx.x)*4;
  int4 v = {NN, NN, NN, NN};
  *(int4*)&csr[i] = v;
}

__global__ void k_fill(const int* __restrict__ es, const int* __restrict__ ed,
                       int* __restrict__ cursor, int* __restrict__ csr){
  int e = blockIdx.x*256 + threadIdx.x;
  if (e < NE){
    int pos = atomicAdd(&cursor[ed[e]], 1);
    csr[pos] = es[e];
  }
}

// ---- weight prep ----
__global__ __launch_bounds__(256) void k_wc(const float* __restrict__ W,
        const float* __restrict__ wih, float* __restrict__ Wc){
  int idx = blockIdx.x*256 + threadIdx.x;
  if (idx >= NL*H*450) return;
  int l = idx / (H*450);
  int rem = idx - l*H*450;
  int k = rem / 450;
  int j = rem - k*450;
  const float* Wr = W   + (size_t)l*H*H + (size_t)k*H;
  const float* wr = wih + (size_t)j*H;
  float acc = 0.f;
  for (int t = 0; t < H; ++t) acc = fmaf(Wr[t], wr[t], acc);
  Wc[idx] = acc;
}

__global__ void k_packi(const float* __restrict__ Wc, short* __restrict__ wbi){
  int idx = blockIdx.x*256 + threadIdx.x;    // NL*10*5*3*512
  int li = idx & 511;
  int q = idx >> 9;
  int mat = q % 3; q /= 3;
  int ks = q % 5;  q /= 5;
  int ct = q % 10; int l = q / 10;
  int lane = li >> 3, j = li & 7;
  int k = ks*32 + ((lane >> 4) << 3) + j;
  int col = ct*16 + (lane & 15);
  float v = (k < H && col < H) ? Wc[(size_t)l*H*450 + (size_t)k*450 + mat*H + col] : 0.f;
  wbi[idx] = (short)f2bf(v);
}

__global__ void k_packh(const float* __restrict__ whh, short* __restrict__ wbh){
  int idx = blockIdx.x*256 + threadIdx.x;    // 10*5*3*512
  int li = idx & 511;
  int q = idx >> 9;
  int mat = q % 3; q /= 3;
  int ks = q % 5;  int ct = q / 5;
  int lane = li >> 3, j = li & 7;
  int k = ks*32 + ((lane >> 4) << 3) + j;
  int col = ct*16 + (lane & 15);
  float v = (k < H && col < H) ? whh[(size_t)(mat*H + col)*H + k] : 0.f;
  wbh[idx] = (short)f2bf(v);
}

__global__ void k_packg(const float* __restrict__ gw1, short* __restrict__ gw1b){
  int idx = blockIdx.x*256 + threadIdx.x;    // 13*5*512
  int li = idx & 511;
  int q = idx >> 9;
  int ks = q % 5;  int ct = q / 5;
  int lane = li >> 3, j = li & 7;
  int k = ks*32 + ((lane >> 4) << 3) + j;
  int col = ct*16 + (lane & 15);
  float v = (k < H && col < GH) ? gw1[(size_t)k*GH + col] : 0.f;
  gw1b[idx] = (short)f2bf(v);
}

__global__ void k_cvt(const float* __restrict__ x, short* __restrict__ hb){
  int idx = blockIdx.x*256 + threadIdx.x;    // NN*80
  if (idx >= NN*80) return;
  int n = idx / 80, c2 = idx - n*80;
  int c = c2*2;
  float lo = (c   < H) ? x[(size_t)n*H + c]   : 0.f;
  float hi = (c+1 < H) ? x[(size_t)n*H + c+1] : 0.f;
  ((u32*)hb)[idx] = (u32)f2bf(lo) | ((u32)f2bf(hi) << 16);
}

// zero the dummy row NN in both state buffers
__global__ void k_zrow(short* __restrict__ a, short* __restrict__ b){
  int t = threadIdx.x;
  if (t < 80){
    ((u32*)a)[(size_t)NN*80 + t] = 0u;
    ((u32*)b)[(size_t)NN*80 + t] = 0u;
  }
}

// aggb[n] = sum over padded segment (pads hit zero dummy row) — no tail loop
__global__ __launch_bounds__(256) void k_gather(const short* __restrict__ hb,
        const int* __restrict__ rowptr, const int* __restrict__ csr,
        short* __restrict__ aggb){
  const int lane = threadIdx.x & 63;
  const int n = blockIdx.x*4 + (threadIdx.x >> 6);
  if (n >= NN) return;
  const int s0 = rowptr[n], s1 = rowptr[n+1];
  const u32* h32 = (const u32*)hb;
  const bool ext = lane < 16;
  float x0=0.f, x1=0.f, y0=0.f, y1=0.f;
  for (int j = s0; j < s1; j += 8){
    int4 ia = *(const int4*)&csr[j];
    int4 ib = *(const int4*)&csr[j+4];
    const u32* r0 = h32 + (size_t)ia.x*80;
    const u32* r1 = h32 + (size_t)ia.y*80;
    const u32* r2 = h32 + (size_t)ia.z*80;
    const u32* r3 = h32 + (size_t)ia.w*80;
    const u32* r4 = h32 + (size_t)ib.x*80;
    const u32* r5 = h32 + (size_t)ib.y*80;
    const u32* r6 = h32 + (size_t)ib.z*80;
    const u32* r7 = h32 + (size_t)ib.w*80;
    u32 v0 = r0[lane], v1 = r1[lane], v2 = r2[lane], v3 = r3[lane];
    u32 v4 = r4[lane], v5 = r5[lane], v6 = r6[lane], v7 = r7[lane];
    u32 u0=0,u1=0,u2=0,u3=0,u4=0,u5=0,u6=0,u7=0;
    if (ext){
      u0 = r0[64+lane]; u1 = r1[64+lane]; u2 = r2[64+lane]; u3 = r3[64+lane];
      u4 = r4[64+lane]; u5 = r5[64+lane]; u6 = r6[64+lane]; u7 = r7[64+lane];
    }
    x0 += bf2f(v0 & 0xffffu) + bf2f(v1 & 0xffffu) + bf2f(v2 & 0xffffu) + bf2f(v3 & 0xffffu)
        + bf2f(v4 & 0xffffu) + bf2f(v5 & 0xffffu) + bf2f(v6 & 0xffffu) + bf2f(v7 & 0xffffu);
    x1 += bf2f(v0 >> 16) + bf2f(v1 >> 16) + bf2f(v2 >> 16) + bf2f(v3 >> 16)
        + bf2f(v4 >> 16) + bf2f(v5 >> 16) + bf2f(v6 >> 16) + bf2f(v7 >> 16);
    if (ext){
      y0 += bf2f(u0 & 0xffffu) + bf2f(u1 & 0xffffu) + bf2f(u2 & 0xffffu) + bf2f(u3 & 0xffffu)
          + bf2f(u4 & 0xffffu) + bf2f(u5 & 0xffffu) + bf2f(u6 & 0xffffu) + bf2f(u7 & 0xffffu);
      y1 += bf2f(u0 >> 16) + bf2f(u1 >> 16) + bf2f(u2 >> 16) + bf2f(u3 >> 16)
          + bf2f(u4 >> 16) + bf2f(u5 >> 16) + bf2f(u6 >> 16) + bf2f(u7 >> 16);
    }
  }
  u32* o = (u32*)aggb + (size_t)n*80;
  o[lane] = pack2(x0, x1);
  if (ext) o[64+lane] = pack2(y0, y1);
}

// ---- GRU via MFMA; A/H in registers (global-loaded), B streamed via LDS ----
__global__ __launch_bounds__(256, 2) void k_gru(
    const short* __restrict__ aggb, const short* __restrict__ hbc,
    short* __restrict__ hbn,
    const short* __restrict__ wbi_l, const short* __restrict__ wbh,
    const float* __restrict__ bih, const float* __restrict__ bhh){
  __shared__ short sB[30*512];   // slots 0..14: gi (ks*3+mat); 15..29: gh
  const int tid = threadIdx.x;
  const int w = tid >> 6, lane = tid & 63;
  const int l16 = lane & 15, g = lane >> 4, g8 = g*8;
  const int row0 = blockIdx.x*128 + w*32;

  bf16x8 fA[2][5], fH[2][5];
  #pragma unroll
  for (int t = 0; t < 2; ++t){
    const int r = row0 + t*16 + l16;
    const bool rv = r < NN;
    #pragma unroll
    for (int ks = 0; ks < 5; ++ks){
      bf16x8 va = {0,0,0,0,0,0,0,0}, vh = {0,0,0,0,0,0,0,0};
      if (rv){
        va = *(const bf16x8*)&aggb[(size_t)r*HS + ks*32 + g8];
        vh = *(const bf16x8*)&hbc [(size_t)r*HS + ks*32 + g8];
      }
      fA[t][ks] = va; fH[t][ks] = vh;
    }
  }

  bf16x8 pr[8];
  #pragma unroll
  for (int k2 = 0; k2 < 8; ++k2){
    int u = tid + k2*256;
    if (u < 1920){
      int s = u >> 6, e = u & 63;
      const short* src = (s < 15) ? (wbi_l + s*512 + e*8)
                                  : (wbh  + (s-15)*512 + e*8);
      pr[k2] = *(const bf16x8*)src;
    }
  }

  for (int ct = 0; ct < 10; ++ct){
    __syncthreads();
    #pragma unroll
    for (int k2 = 0; k2 < 8; ++k2){
      int u = tid + k2*256;
      if (u < 1920) *(bf16x8*)&sB[u*8] = pr[k2];
    }
    __syncthreads();
    if (ct < 9){
      const int cto = (ct+1)*7680;
      #pragma unroll
      for (int k2 = 0; k2 < 8; ++k2){
        int u = tid + k2*256;
        if (u < 1920){
          int s = u >> 6, e = u & 63;
          const short* src = (s < 15) ? (wbi_l + cto + s*512 + e*8)
                                      : (wbh  + cto + (s-15)*512 + e*8);
          pr[k2] = *(const bf16x8*)src;
        }
      }
    }

    const int col = ct*16 + l16;
    const bool cv = col < H;
    const float bir = cv ? bih[col] : 0.f, biz = cv ? bih[H+col] : 0.f, bin_ = cv ? bih[2*H+col] : 0.f;
    const float bhr = cv ? bhh[col] : 0.f, bhz = cv ? bhh[H+col] : 0.f, bhn  = cv ? bhh[2*H+col] : 0.f;

    f32x4 ai[2][3], ah[2][3];
    #pragma unroll
    for (int t = 0; t < 2; ++t)
      #pragma unroll
      for (int m = 0; m < 3; ++m){ ai[t][m] = (f32x4){0,0,0,0}; ah[t][m] = (f32x4){0,0,0,0}; }

    #pragma unroll
    for (int ks = 0; ks < 5; ++ks){
      bf16x8 bi0 = *(const bf16x8*)&sB[(ks*3+0)*512 + lane*8];
      bf16x8 bi1 = *(const bf16x8*)&sB[(ks*3+1)*512 + lane*8];
      bf16x8 bi2 = *(const bf16x8*)&sB[(ks*3+2)*512 + lane*8];
      bf16x8 bh0 = *(const bf16x8*)&sB[(15+ks*3+0)*512 + lane*8];
      bf16x8 bh1 = *(const bf16x8*)&sB[(15+ks*3+1)*512 + lane*8];
      bf16x8 bh2 = *(const bf16x8*)&sB[(15+ks*3+2)*512 + lane*8];
      #pragma unroll
      for (int t = 0; t < 2; ++t){
        ai[t][0] = __builtin_amdgcn_mfma_f32_16x16x32_bf16(fA[t][ks], bi0, ai[t][0], 0,0,0);
        ai[t][1] = __builtin_amdgcn_mfma_f32_16x16x32_bf16(fA[t][ks], bi1, ai[t][1], 0,0,0);
        ai[t][2] = __builtin_amdgcn_mfma_f32_16x16x32_bf16(fA[t][ks], bi2, ai[t][2], 0,0,0);
        ah[t][0] = __builtin_amdgcn_mfma_f32_16x16x32_bf16(fH[t][ks], bh0, ah[t][0], 0,0,0);
        ah[t][1] = __builtin_amdgcn_mfma_f32_16x16x32_bf16(fH[t][ks], bh1, ah[t][1], 0,0,0);
        ah[t][2] = __builtin_amdgcn_mfma_f32_16x16x32_bf16(fH[t][ks], bh2, ah[t][2], 0,0,0);
      }
    }

    if (cv){
      #pragma unroll
      for (int t = 0; t < 2; ++t){
        #pragma unroll
        for (int r = 0; r < 4; ++r){
          int grow = row0 + t*16 + g*4 + r;
          if (grow < NN){
            float rr = fast_sig(ai[t][0][r]+bir + ah[t][0][r]+bhr);
            float zz = fast_sig(ai[t][1][r]+biz + ah[t][1][r]+bhz);
            float nn = fast_tanh(ai[t][2][r]+bin_ + rr*(ah[t][2][r]+bhn));
            float hold = bf2f((u32)(u16)hbc[(size_t)grow*HS + col]);
            float hnew = (1.f-zz)*nn + zz*hold;
            hbn[(size_t)grow*HS + col] = (short)f2bf(hnew);
          }
        }
      }
    }
  }
}

// gate_pre via MFMA
__global__ __launch_bounds__(256) void k_gatepre(const short* __restrict__ hb,
      const short* __restrict__ gw1b, const float* __restrict__ gb1,
      const float* __restrict__ gw2, const float* __restrict__ gb2,
      float* __restrict__ gbuf){
  __shared__ short sh[64*LS];
  __shared__ float part[4][4][4][4];
  const int tid = threadIdx.x;
  const int w = tid >> 6, lane = tid & 63;
  const int l16 = lane & 15, g = lane >> 4, g8 = g*8;
  const int chunk = blockIdx.x, row0 = chunk*64;

  for (int i = tid; i < 64*20; i += 256){
    int r = i/20, c = i - r*20;
    int gr = row0 + r;
    bf16x8 v = {0,0,0,0,0,0,0,0};
    if (gr < NN) v = *(const bf16x8*)&hb[(size_t)gr*HS + c*8];
    *(bf16x8*)&sh[r*LS + c*8] = v;
  }
  __syncthreads();

  float acc[4][4];
  #pragma unroll
  for (int rt=0; rt<4; ++rt){
    #pragma unroll
    for (int r=0; r<4; ++r) acc[rt][r] = 0.f;
  }
  for (int ct = w; ct < 13; ct += 4){
    bf16x8 B[5];
    const short* p = gw1b + (size_t)(ct*5)*512 + lane*8;
    #pragma unroll
    for (int ks = 0; ks < 5; ++ks) B[ks] = *(const bf16x8*)&p[ks*512];
    int col = ct*16 + l16;
    bool cv = col < GH;
    float g2 = cv ? gw2[col] : 0.f;
    float b1 = cv ? gb1[col] : 0.f;
    #pragma unroll
    for (int rt = 0; rt < 4; ++rt){
      f32x4 d = {0,0,0,0};
      #pragma unroll
      for (int ks = 0; ks < 5; ++ks){
        bf16x8 aH = *(const bf16x8*)&sh[(rt*16 + l16)*LS + ks*32 + g8];
        d = __builtin_amdgcn_mfma_f32_16x16x32_bf16(aH, B[ks], d, 0,0,0);
      }
      if (cv){
        #pragma unroll
        for (int r = 0; r < 4; ++r) acc[rt][r] += fast_tanh(d[r] + b1) * g2;
      }
    }
  }
  #pragma unroll
  for (int rt = 0; rt < 4; ++rt){
    #pragma unroll
    for (int r = 0; r < 4; ++r){
      float v = acc[rt][r];
      v += __shfl_xor(v, 1); v += __shfl_xor(v, 2);
      v += __shfl_xor(v, 4); v += __shfl_xor(v, 8);
      if (l16 == 0) part[w][rt][g][r] = v;
    }
  }
  __syncthreads();
  if (tid < 64){
    int rt = tid >> 4, gg = (tid >> 2) & 3, r = tid & 3;
    int grow = row0 + tid;
    if (grow < NN)
      gbuf[grow] = part[0][rt][gg][r] + part[1][rt][gg][r]
                 + part[2][rt][gg][r] + part[3][rt][gg][r] + gb2[0];
  }
}

// per-graph segment softmax + weighted sum (bf16 h)
__global__ __launch_bounds__(256) void k_readout(float* __restrict__ gatebuf,
    const short* __restrict__ hb, const int* __restrict__ batch,
    float* __restrict__ out, float* __restrict__ gate_out){
  const int g = blockIdx.x;
  const int tid = threadIdx.x;
  int lo=0, hi=NN;
  while (lo<hi){ int mid=(lo+hi)>>1; if (batch[mid] < g) lo=mid+1; else hi=mid; }
  const int start = lo;
  hi = NN;
  while (lo<hi){ int mid=(lo+hi)>>1; if (batch[mid] < g+1) lo=mid+1; else hi=mid; }
  const int end = lo;

  __shared__ float red[256];
  __shared__ float s_max, s_inv;
  float mx = -INFINITY;
  for (int n = start+tid; n < end; n += 256) mx = fmaxf(mx, gatebuf[n]);
  red[tid]=mx; __syncthreads();
  for (int s=128; s>=1; s>>=1){ if (tid<s) red[tid]=fmaxf(red[tid],red[tid+s]); __syncthreads(); }
  if (tid==0) s_max = red[0];
  __syncthreads();
  const float gmax = s_max;
  float sum = 0.f;
  for (int n = start+tid; n < end; n += 256){
    float e = expf(gatebuf[n]-gmax);
    gatebuf[n] = e;
    sum += e;
  }
  red[tid]=sum; __syncthreads();
  for (int s=128; s>=1; s>>=1){ if (tid<s) red[tid]+=red[tid+s]; __syncthreads(); }
  if (tid==0) s_inv = 1.0f/(red[0] + 1e-16f);
  __syncthreads();
  const float inv = s_inv;
  for (int n = start+tid; n < end; n += 256) gate_out[n] = gatebuf[n]*inv;
  if (tid < 80){
    const u32* h32 = (const u32*)hb;
    float acc0 = 0.f, acc1 = 0.f;
    for (int n = start; n < end; ++n){
      u32 v = h32[(size_t)n*80 + tid];
      float gv = gatebuf[n];
      acc0 = fmaf(gv, bf2f(v & 0xffffu), acc0);
      acc1 = fmaf(gv, bf2f(v >> 16),     acc1);
    }
    int c0 = 2*tid, c1 = 2*tid + 1;
    if (c0 < H) out[g*H + c0] = acc0*inv;
    if (c1 < H) out[g*H + c1] = acc1*inv;
  }
}

extern "C" void kernel_launch(void* const* d_in, const int* in_sizes, int n_in,
                              void* d_out, int out_size, void* d_ws, size_t ws_size,
                              hipStream_t stream) {
  (void)in_sizes; (void)n_in; (void)out_size; (void)ws_size;
  const float* x    = (const float*)d_in[0];
  const int*   eidx = (const int*)d_in[1];
  const int*   batch= (const int*)d_in[2];
  const float* W    = (const float*)d_in[3];
  const float* wih  = (const float*)d_in[4];
  const float* whh  = (const float*)d_in[5];
  const float* bih  = (const float*)d_in[6];
  const float* bhh  = (const float*)d_in[7];
  const float* gw1  = (const float*)d_in[8];
  const float* gb1  = (const float*)d_in[9];
  const float* gw2  = (const float*)d_in[10];
  const float* gb2  = (const float*)d_in[11];

  float* out      = (float*)d_out;
  float* gate_out = out + NG*H;

  char* p = (char*)d_ws;
  float* gbuf  = (float*)p;  p += (size_t)NN*4;
  float* Wc    = (float*)p;  p += (size_t)NL*H*450*4;
  short* hb0   = (short*)p;  p += (size_t)(NN+1)*HS*2;
  short* hb1   = (short*)p;  p += (size_t)(NN+1)*HS*2;
  short* aggb  = (short*)p;  p += (size_t)NN*HS*2;
  short* wbi   = (short*)p;  p += (size_t)NL*76800*2;
  short* wbh   = (short*)p;  p += (size_t)76800*2;
  short* gw1b  = (short*)p;  p += (size_t)33280*2;
  int*   cnt   = (int*)p;    p += (size_t)NN*4;
  int*   rowptr= (int*)p;    p += (size_t)(NN+1)*4;
  int*   cursor= (int*)p;    p += (size_t)NN*4;
  int*   csr   = (int*)p;    p += (size_t)CSRMAX*4;
  int*   spart = (int*)p;    p += (size_t)SNB*4;

  const int* esrc = eidx;
  const int* edst = eidx + NE;

  hipMemsetAsync(cnt, 0, sizeof(int)*NN, stream);
  k_hist<<<(NE+255)/256, 256, 0, stream>>>(edst, cnt);
  k_scan1<<<SNB, 256, 0, stream>>>(cnt, spart);
  k_scan2<<<1, 64, 0, stream>>>(spart);
  k_scan3<<<SNB, 1024, 0, stream>>>(cnt, spart, rowptr, cursor);
  k_pre <<<CSRMAX/1024, 256, 0, stream>>>(csr);
  k_fill<<<(NE+255)/256, 256, 0, stream>>>(esrc, edst, cursor, csr);

  k_wc   <<<(NL*H*450+255)/256, 256, 0, stream>>>(W, wih, Wc);
  k_packi<<<1500, 256, 0, stream>>>(Wc, wbi);
  k_packh<<<300,  256, 0, stream>>>(whh, wbh);
  k_packg<<<130,  256, 0, stream>>>(gw1, gw1b);

  k_cvt<<<(NN*80+255)/256, 256, 0, stream>>>(x, hb0);
  k_zrow<<<1, 128, 0, stream>>>(hb0, hb1);

  for (int l = 0; l < NL; ++l){
    short* cur  = (l & 1) ? hb1 : hb0;
    short* next = (l & 1) ? hb0 : hb1;
    k_gather<<<NN/4, 256, 0, stream>>>(cur, rowptr, csr, aggb);
    k_gru<<<CH2, 256, 0, stream>>>(aggb, cur, next,
                                   wbi + (size_t)l*76800, wbh, bih, bhh);
  }
  k_gatepre<<<CHN, 256, 0, stream>>>(hb1, gw1b, gb1, gw2, gb2, gbuf);
  k_readout<<<NG, 256, 0, stream>>>(gbuf, hb1, batch, out, gate_out);
}

// Round 10
// 1232.028 us; speedup vs baseline: 2.8842x; 1.0074x over previous
//
#include <hip/hip_runtime.h>
#include <math.h>

#define NN 100000
#define NE 1600000
#define H 150
#define NG 256
#define NL 5
#define GH 200
#define HS 160          // padded bf16 row stride (elements)
#define LS 168          // LDS row stride in bf16 elems (gatepre)
#define CHN 1563        // ceil(NN/64)
#define CH2 782         // ceil(NN/128)
#define SNB 98          // ceil(NN/1024)
#define CSRMAX 2304000  // >= NE + 7*NN, divisible by 1024
#define NB 196          // buckets of 512 nodes
#define EBLK 782        // ceil(NE/2048)

typedef unsigned short u16;
typedef unsigned int   u32;
typedef __attribute__((ext_vector_type(8))) short bf16x8;
typedef __attribute__((ext_vector_type(4))) float f32x4;

__device__ __forceinline__ float bf2f(u32 lo16){ u32 t = lo16 << 16; return __builtin_bit_cast(float, t); }
__device__ __forceinline__ u16 f2bf(float f){
  u32 u = __builtin_bit_cast(u32, f);
  u += 0x7fffu + ((u >> 16) & 1u);
  return (u16)(u >> 16);
}
__device__ __forceinline__ u32 pack2(float a, float b){ return (u32)f2bf(a) | ((u32)f2bf(b) << 16); }
__device__ __forceinline__ float fast_sig(float x){
  float e = __expf(-x);
  return __builtin_amdgcn_rcpf(1.f + e);
}
__device__ __forceinline__ float fast_tanh(float x){
  float cx = fminf(fmaxf(x, -15.f), 15.f);
  float e = __expf(2.f*cx);
  return (e - 1.f) * __builtin_amdgcn_rcpf(e + 1.f);
}

// ---- CSR build ----
__global__ void k_hist(const int* __restrict__ ed, int* __restrict__ cnt){
  int e = blockIdx.x*256 + threadIdx.x;
  if (e < NE) atomicAdd(&cnt[ed[e]], 1);
}

// padded partial sums: sum of (cnt+7)&~7 per 1024-chunk
__global__ __launch_bounds__(256) void k_scan1(const int* __restrict__ cnt, int* __restrict__ part){
  __shared__ int red[256];
  const int b = blockIdx.x, tid = threadIdx.x;
  const int base = b*1024;
  int s = 0;
  #pragma unroll
  for (int i = 0; i < 4; ++i){
    int idx = base + tid + i*256;
    int v = (idx < NN) ? cnt[idx] : 0;
    s += (v + 7) & ~7;
  }
  red[tid] = s; __syncthreads();
  for (int st = 128; st >= 1; st >>= 1){
    if (tid < st) red[tid] += red[tid+st];
    __syncthreads();
  }
  if (tid == 0) part[b] = red[0];
}

__global__ void k_scan2(int* __restrict__ part){
  const int t = threadIdx.x;
  int v0 = (2*t   < SNB) ? part[2*t]   : 0;
  int v1 = (2*t+1 < SNB) ? part[2*t+1] : 0;
  int s = v0 + v1, x = s;
  #pragma unroll
  for (int off = 1; off < 64; off <<= 1){
    int tt = __shfl_up(x, off);
    if (t >= off) x += tt;
  }
  int excl = x - s;
  if (2*t   < SNB) part[2*t]   = excl;
  if (2*t+1 < SNB) part[2*t+1] = excl + v0;
}

// padded local scan -> rowptr (padded), cursor (padded segment start)
__global__ __launch_bounds__(1024) void k_scan3(const int* __restrict__ cnt,
        const int* __restrict__ part, int* __restrict__ rowptr, int* __restrict__ cursor){
  __shared__ int wsum[16];
  const int b = blockIdx.x, tid = threadIdx.x;
  const int wid = tid >> 6, lane = tid & 63;
  const int idx = b*1024 + tid;
  int c = (idx < NN) ? cnt[idx] : 0;
  int v = (c + 7) & ~7;
  int x = v;
  #pragma unroll
  for (int off = 1; off < 64; off <<= 1){
    int t = __shfl_up(x, off);
    if (lane >= off) x += t;
  }
  if (lane == 63) wsum[wid] = x;
  __syncthreads();
  if (tid < 16){
    int s = wsum[tid];
    int y = s;
    #pragma unroll
    for (int off = 1; off < 16; off <<= 1){
      int t = __shfl_up(y, off);
      if (tid >= off) y += t;
    }
    wsum[tid] = y - s;
  }
  __syncthreads();
  if (idx < NN){
    int incl = part[b] + wsum[wid] + x;
    rowptr[idx+1] = incl;
    cursor[idx]   = incl - v;
  }
  if (idx == 0) rowptr[0] = 0;
}

// prefill csr with dummy index NN (coalesced int4 stores)
__global__ __launch_bounds__(256) void k_pre(int* __restrict__ csr){
  int i = (blockIdx.x*256 + threadIdx.x)*4;
  int4 v = {NN, NN, NN, NN};
  *(int4*)&csr[i] = v;
}

// ---- bucket sort of edges by dst>>9 (write-locality for csr fill) ----
__global__ __launch_bounds__(256) void k_bhist(const int* __restrict__ ed, int* __restrict__ bcnt){
  __shared__ int bh[NB];
  const int tid = threadIdx.x;
  for (int i = tid; i < NB; i += 256) bh[i] = 0;
  __syncthreads();
  const int base = blockIdx.x*2048;
  #pragma unroll
  for (int i = 0; i < 8; ++i){
    int e = base + i*256 + tid;
    if (e < NE) atomicAdd(&bh[ed[e] >> 9], 1);
  }
  __syncthreads();
  for (int i = tid; i < NB; i += 256) if (bh[i]) atomicAdd(&bcnt[i], bh[i]);
}

__global__ void k_bscan(const int* __restrict__ bcnt, int* __restrict__ bcur){
  __shared__ int ws[4];
  const int t = threadIdx.x, lane = t & 63, w = t >> 6;
  int v = (t < NB) ? bcnt[t] : 0;
  int x = v;
  #pragma unroll
  for (int off = 1; off < 64; off <<= 1){
    int tt = __shfl_up(x, off);
    if (lane >= off) x += tt;
  }
  if (lane == 63) ws[w] = x;
  __syncthreads();
  if (t == 0){
    int s = 0;
    #pragma unroll
    for (int i = 0; i < 4; ++i){ int tmp = ws[i]; ws[i] = s; s += tmp; }
  }
  __syncthreads();
  if (t < NB) bcur[t] = ws[w] + x - v;
}

__global__ __launch_bounds__(256) void k_bscatter(const int* __restrict__ es,
        const int* __restrict__ ed, int* __restrict__ bcur, int2* __restrict__ ebuf){
  __shared__ int lh[NB];
  __shared__ int lbase[NB];
  const int tid = threadIdx.x;
  for (int i = tid; i < NB; i += 256) lh[i] = 0;
  __syncthreads();
  const int base = blockIdx.x*2048;
  u32 meta[8]; int srcs[8], dsts[8];
  #pragma unroll
  for (int i = 0; i < 8; ++i){
    int e = base + i*256 + tid;
    if (e < NE){
      int d = ed[e];
      int b = d >> 9;
      int lr = atomicAdd(&lh[b], 1);
      meta[i] = ((u32)b << 16) | (u32)lr;
      srcs[i] = es[e]; dsts[i] = d;
    } else meta[i] = 0xffffffffu;
  }
  __syncthreads();
  for (int i = tid; i < NB; i += 256){
    int c = lh[i];
    lbase[i] = c ? atomicAdd(&bcur[i], c) : 0;
  }
  __syncthreads();
  #pragma unroll
  for (int i = 0; i < 8; ++i){
    if (meta[i] != 0xffffffffu){
      int b = meta[i] >> 16, lr = meta[i] & 0xffff;
      ebuf[lbase[b] + lr] = make_int2(srcs[i], dsts[i]);
    }
  }
}

// consume bucket-grouped edges: csr writes land in ~40KB windows -> L2-merged
__global__ void k_fill2(const int2* __restrict__ ebuf, int* __restrict__ cursor,
                        int* __restrict__ csr){
  int e = blockIdx.x*256 + threadIdx.x;
  if (e < NE){
    int2 sd = ebuf[e];
    int pos = atomicAdd(&cursor[sd.y], 1);
    csr[pos] = sd.x;
  }
}

// ---- weight prep ----
__global__ __launch_bounds__(256) void k_wc(const float* __restrict__ W,
        const float* __restrict__ wih, float* __restrict__ Wc){
  int idx = blockIdx.x*256 + threadIdx.x;
  if (idx >= NL*H*450) return;
  int l = idx / (H*450);
  int rem = idx - l*H*450;
  int k = rem / 450;
  int j = rem - k*450;
  const float* Wr = W   + (size_t)l*H*H + (size_t)k*H;
  const float* wr = wih + (size_t)j*H;
  float acc = 0.f;
  for (int t = 0; t < H; ++t) acc = fmaf(Wr[t], wr[t], acc);
  Wc[idx] = acc;
}

__global__ void k_packi(const float* __restrict__ Wc, short* __restrict__ wbi){
  int idx = blockIdx.x*256 + threadIdx.x;    // NL*10*5*3*512
  int li = idx & 511;
  int q = idx >> 9;
  int mat = q % 3; q /= 3;
  int ks = q % 5;  q /= 5;
  int ct = q % 10; int l = q / 10;
  int lane = li >> 3, j = li & 7;
  int k = ks*32 + ((lane >> 4) << 3) + j;
  int col = ct*16 + (lane & 15);
  float v = (k < H && col < H) ? Wc[(size_t)l*H*450 + (size_t)k*450 + mat*H + col] : 0.f;
  wbi[idx] = (short)f2bf(v);
}

__global__ void k_packh(const float* __restrict__ whh, short* __restrict__ wbh){
  int idx = blockIdx.x*256 + threadIdx.x;    // 10*5*3*512
  int li = idx & 511;
  int q = idx >> 9;
  int mat = q % 3; q /= 3;
  int ks = q % 5;  int ct = q / 5;
  int lane = li >> 3, j = li & 7;
  int k = ks*32 + ((lane >> 4) << 3) + j;
  int col = ct*16 + (lane & 15);
  float v = (k < H && col < H) ? whh[(size_t)(mat*H + col)*H + k] : 0.f;
  wbh[idx] = (short)f2bf(v);
}

__global__ void k_packg(const float* __restrict__ gw1, short* __restrict__ gw1b){
  int idx = blockIdx.x*256 + threadIdx.x;    // 13*5*512
  int li = idx & 511;
  int q = idx >> 9;
  int ks = q % 5;  int ct = q / 5;
  int lane = li >> 3, j = li & 7;
  int k = ks*32 + ((lane >> 4) << 3) + j;
  int col = ct*16 + (lane & 15);
  float v = (k < H && col < GH) ? gw1[(size_t)k*GH + col] : 0.f;
  gw1b[idx] = (short)f2bf(v);
}

__global__ void k_cvt(const float* __restrict__ x, short* __restrict__ hb){
  int idx = blockIdx.x*256 + threadIdx.x;    // NN*80
  if (idx >= NN*80) return;
  int n = idx / 80, c2 = idx - n*80;
  int c = c2*2;
  float lo = (c   < H) ? x[(size_t)n*H + c]   : 0.f;
  float hi = (c+1 < H) ? x[(size_t)n*H + c+1] : 0.f;
  ((u32*)hb)[idx] = (u32)f2bf(lo) | ((u32)f2bf(hi) << 16);
}

// zero the dummy row NN in both state buffers
__global__ void k_zrow(short* __restrict__ a, short* __restrict__ b){
  int t = threadIdx.x;
  if (t < 80){
    ((u32*)a)[(size_t)NN*80 + t] = 0u;
    ((u32*)b)[(size_t)NN*80 + t] = 0u;
  }
}

// aggb[n] = sum over padded segment (pads hit zero dummy row) — no tail loop
__global__ __launch_bounds__(256) void k_gather(const short* __restrict__ hb,
        const int* __restrict__ rowptr, const int* __restrict__ csr,
        short* __restrict__ aggb){
  const int lane = threadIdx.x & 63;
  const int n = blockIdx.x*4 + (threadIdx.x >> 6);
  if (n >= NN) return;
  const int s0 = rowptr[n], s1 = rowptr[n+1];
  const u32* h32 = (const u32*)hb;
  const bool ext = lane < 16;
  float x0=0.f, x1=0.f, y0=0.f, y1=0.f;
  for (int j = s0; j < s1; j += 8){
    int4 ia = *(const int4*)&csr[j];
    int4 ib = *(const int4*)&csr[j+4];
    const u32* r0 = h32 + (size_t)ia.x*80;
    const u32* r1 = h32 + (size_t)ia.y*80;
    const u32* r2 = h32 + (size_t)ia.z*80;
    const u32* r3 = h32 + (size_t)ia.w*80;
    const u32* r4 = h32 + (size_t)ib.x*80;
    const u32* r5 = h32 + (size_t)ib.y*80;
    const u32* r6 = h32 + (size_t)ib.z*80;
    const u32* r7 = h32 + (size_t)ib.w*80;
    u32 v0 = r0[lane], v1 = r1[lane], v2 = r2[lane], v3 = r3[lane];
    u32 v4 = r4[lane], v5 = r5[lane], v6 = r6[lane], v7 = r7[lane];
    u32 u0=0,u1=0,u2=0,u3=0,u4=0,u5=0,u6=0,u7=0;
    if (ext){
      u0 = r0[64+lane]; u1 = r1[64+lane]; u2 = r2[64+lane]; u3 = r3[64+lane];
      u4 = r4[64+lane]; u5 = r5[64+lane]; u6 = r6[64+lane]; u7 = r7[64+lane];
    }
    x0 += bf2f(v0 & 0xffffu) + bf2f(v1 & 0xffffu) + bf2f(v2 & 0xffffu) + bf2f(v3 & 0xffffu)
        + bf2f(v4 & 0xffffu) + bf2f(v5 & 0xffffu) + bf2f(v6 & 0xffffu) + bf2f(v7 & 0xffffu);
    x1 += bf2f(v0 >> 16) + bf2f(v1 >> 16) + bf2f(v2 >> 16) + bf2f(v3 >> 16)
        + bf2f(v4 >> 16) + bf2f(v5 >> 16) + bf2f(v6 >> 16) + bf2f(v7 >> 16);
    if (ext){
      y0 += bf2f(u0 & 0xffffu) + bf2f(u1 & 0xffffu) + bf2f(u2 & 0xffffu) + bf2f(u3 & 0xffffu)
          + bf2f(u4 & 0xffffu) + bf2f(u5 & 0xffffu) + bf2f(u6 & 0xffffu) + bf2f(u7 & 0xffffu);
      y1 += bf2f(u0 >> 16) + bf2f(u1 >> 16) + bf2f(u2 >> 16) + bf2f(u3 >> 16)
          + bf2f(u4 >> 16) + bf2f(u5 >> 16) + bf2f(u6 >> 16) + bf2f(u7 >> 16);
    }
  }
  u32* o = (u32*)aggb + (size_t)n*80;
  o[lane] = pack2(x0, x1);
  if (ext) o[64+lane] = pack2(y0, y1);
}

// ---- GRU via MFMA; A/H in registers, B double-buffered via LDS (1 barrier/ct) ----
__global__ __launch_bounds__(256, 2) void k_gru(
    const short* __restrict__ aggb, const short* __restrict__ hbc,
    short* __restrict__ hbn,
    const short* __restrict__ wbi_l, const short* __restrict__ wbh,
    const float* __restrict__ bih, const float* __restrict__ bhh){
  __shared__ short sB[2][15360];   // per buf: slots 0..14 gi, 15..29 gh (512 elems each)
  const int tid = threadIdx.x;
  const int w = tid >> 6, lane = tid & 63;
  const int l16 = lane & 15, g = lane >> 4, g8 = g*8;
  const int row0 = blockIdx.x*128 + w*32;

  bf16x8 fA[2][5], fH[2][5];
  #pragma unroll
  for (int t = 0; t < 2; ++t){
    const int r = row0 + t*16 + l16;
    const bool rv = r < NN;
    #pragma unroll
    for (int ks = 0; ks < 5; ++ks){
      bf16x8 va = {0,0,0,0,0,0,0,0}, vh = {0,0,0,0,0,0,0,0};
      if (rv){
        va = *(const bf16x8*)&aggb[(size_t)r*HS + ks*32 + g8];
        vh = *(const bf16x8*)&hbc [(size_t)r*HS + ks*32 + g8];
      }
      fA[t][ks] = va; fH[t][ks] = vh;
    }
  }

  bf16x8 pr[8];
  // prologue: stage ct=0 into sB[0]
  #pragma unroll
  for (int k2 = 0; k2 < 8; ++k2){
    int u = tid + k2*256;
    if (u < 1920){
      int s = u >> 6, e = u & 63;
      const short* src = (s < 15) ? (wbi_l + s*512 + e*8)
                                  : (wbh  + (s-15)*512 + e*8);
      pr[k2] = *(const bf16x8*)src;
    }
  }
  #pragma unroll
  for (int k2 = 0; k2 < 8; ++k2){
    int u = tid + k2*256;
    if (u < 1920) *(bf16x8*)&sB[0][u*8] = pr[k2];
  }

  for (int ct = 0; ct < 10; ++ct){
    const int cur = ct & 1;
    __syncthreads();   // sB[cur] written; prior readers of sB[cur^1] done
    if (ct < 9){
      const int cto = (ct+1)*7680;
      #pragma unroll
      for (int k2 = 0; k2 < 8; ++k2){
        int u = tid + k2*256;
        if (u < 1920){
          int s = u >> 6, e = u & 63;
          const short* src = (s < 15) ? (wbi_l + cto + s*512 + e*8)
                                      : (wbh  + cto + (s-15)*512 + e*8);
          pr[k2] = *(const bf16x8*)src;
        }
      }
    }

    const int col = ct*16 + l16;
    const bool cv = col < H;
    const float bir = cv ? bih[col] : 0.f, biz = cv ? bih[H+col] : 0.f, bin_ = cv ? bih[2*H+col] : 0.f;
    const float bhr = cv ? bhh[col] : 0.f, bhz = cv ? bhh[H+col] : 0.f, bhn  = cv ? bhh[2*H+col] : 0.f;

    f32x4 ai[2][3], ah[2][3];
    #pragma unroll
    for (int t = 0; t < 2; ++t)
      #pragma unroll
      for (int m = 0; m < 3; ++m){ ai[t][m] = (f32x4){0,0,0,0}; ah[t][m] = (f32x4){0,0,0,0}; }

    const short* sbc = sB[cur];
    #pragma unroll
    for (int ks = 0; ks < 5; ++ks){
      bf16x8 bi0 = *(const bf16x8*)&sbc[(ks*3+0)*512 + lane*8];
      bf16x8 bi1 = *(const bf16x8*)&sbc[(ks*3+1)*512 + lane*8];
      bf16x8 bi2 = *(const bf16x8*)&sbc[(ks*3+2)*512 + lane*8];
      bf16x8 bh0 = *(const bf16x8*)&sbc[(15+ks*3+0)*512 + lane*8];
      bf16x8 bh1 = *(const bf16x8*)&sbc[(15+ks*3+1)*512 + lane*8];
      bf16x8 bh2 = *(const bf16x8*)&sbc[(15+ks*3+2)*512 + lane*8];
      #pragma unroll
      for (int t = 0; t < 2; ++t){
        ai[t][0] = __builtin_amdgcn_mfma_f32_16x16x32_bf16(fA[t][ks], bi0, ai[t][0], 0,0,0);
        ai[t][1] = __builtin_amdgcn_mfma_f32_16x16x32_bf16(fA[t][ks], bi1, ai[t][1], 0,0,0);
        ai[t][2] = __builtin_amdgcn_mfma_f32_16x16x32_bf16(fA[t][ks], bi2, ai[t][2], 0,0,0);
        ah[t][0] = __builtin_amdgcn_mfma_f32_16x16x32_bf16(fH[t][ks], bh0, ah[t][0], 0,0,0);
        ah[t][1] = __builtin_amdgcn_mfma_f32_16x16x32_bf16(fH[t][ks], bh1, ah[t][1], 0,0,0);
        ah[t][2] = __builtin_amdgcn_mfma_f32_16x16x32_bf16(fH[t][ks], bh2, ah[t][2], 0,0,0);
      }
    }

    if (ct < 9){
      #pragma unroll
      for (int k2 = 0; k2 < 8; ++k2){
        int u = tid + k2*256;
        if (u < 1920) *(bf16x8*)&sB[cur^1][u*8] = pr[k2];
      }
    }

    if (cv){
      #pragma unroll
      for (int t = 0; t < 2; ++t){
        #pragma unroll
        for (int r = 0; r < 4; ++r){
          int grow = row0 + t*16 + g*4 + r;
          if (grow < NN){
            float rr = fast_sig(ai[t][0][r]+bir + ah[t][0][r]+bhr);
            float zz = fast_sig(ai[t][1][r]+biz + ah[t][1][r]+bhz);
            float nn = fast_tanh(ai[t][2][r]+bin_ + rr*(ah[t][2][r]+bhn));
            float hold = bf2f((u32)(u16)hbc[(size_t)grow*HS + col]);
            float hnew = (1.f-zz)*nn + zz*hold;
            hbn[(size_t)grow*HS + col] = (short)f2bf(hnew);
          }
        }
      }
    }
  }
}

// gate_pre via MFMA
__global__ __launch_bounds__(256) void k_gatepre(const short* __restrict__ hb,
      const short* __restrict__ gw1b, const float* __restrict__ gb1,
      const float* __restrict__ gw2, const float* __restrict__ gb2,
      float* __restrict__ gbuf){
  __shared__ short sh[64*LS];
  __shared__ float part[4][4][4][4];
  const int tid = threadIdx.x;
  const int w = tid >> 6, lane = tid & 63;
  const int l16 = lane & 15, g = lane >> 4, g8 = g*8;
  const int chunk = blockIdx.x, row0 = chunk*64;

  for (int i = tid; i < 64*20; i += 256){
    int r = i/20, c = i - r*20;
    int gr = row0 + r;
    bf16x8 v = {0,0,0,0,0,0,0,0};
    if (gr < NN) v = *(const bf16x8*)&hb[(size_t)gr*HS + c*8];
    *(bf16x8*)&sh[r*LS + c*8] = v;
  }
  __syncthreads();

  float acc[4][4];
  #pragma unroll
  for (int rt=0; rt<4; ++rt){
    #pragma unroll
    for (int r=0; r<4; ++r) acc[rt][r] = 0.f;
  }
  for (int ct = w; ct < 13; ct += 4){
    bf16x8 B[5];
    const short* p = gw1b + (size_t)(ct*5)*512 + lane*8;
    #pragma unroll
    for (int ks = 0; ks < 5; ++ks) B[ks] = *(const bf16x8*)&p[ks*512];
    int col = ct*16 + l16;
    bool cv = col < GH;
    float g2 = cv ? gw2[col] : 0.f;
    float b1 = cv ? gb1[col] : 0.f;
    #pragma unroll
    for (int rt = 0; rt < 4; ++rt){
      f32x4 d = {0,0,0,0};
      #pragma unroll
      for (int ks = 0; ks < 5; ++ks){
        bf16x8 aH = *(const bf16x8*)&sh[(rt*16 + l16)*LS + ks*32 + g8];
        d = __builtin_amdgcn_mfma_f32_16x16x32_bf16(aH, B[ks], d, 0,0,0);
      }
      if (cv){
        #pragma unroll
        for (int r = 0; r < 4; ++r) acc[rt][r] += fast_tanh(d[r] + b1) * g2;
      }
    }
  }
  #pragma unroll
  for (int rt = 0; rt < 4; ++rt){
    #pragma unroll
    for (int r = 0; r < 4; ++r){
      float v = acc[rt][r];
      v += __shfl_xor(v, 1); v += __shfl_xor(v, 2);
      v += __shfl_xor(v, 4); v += __shfl_xor(v, 8);
      if (l16 == 0) part[w][rt][g][r] = v;
    }
  }
  __syncthreads();
  if (tid < 64){
    int rt = tid >> 4, gg = (tid >> 2) & 3, r = tid & 3;
    int grow = row0 + tid;
    if (grow < NN)
      gbuf[grow] = part[0][rt][gg][r] + part[1][rt][gg][r]
                 + part[2][rt][gg][r] + part[3][rt][gg][r] + gb2[0];
  }
}

// per-graph segment softmax + weighted sum (bf16 h)
__global__ __launch_bounds__(256) void k_readout(float* __restrict__ gatebuf,
    const short* __restrict__ hb, const int* __restrict__ batch,
    float* __restrict__ out, float* __restrict__ gate_out){
  const int g = blockIdx.x;
  const int tid = threadIdx.x;
  int lo=0, hi=NN;
  while (lo<hi){ int mid=(lo+hi)>>1; if (batch[mid] < g) lo=mid+1; else hi=mid; }
  const int start = lo;
  hi = NN;
  while (lo<hi){ int mid=(lo+hi)>>1; if (batch[mid] < g+1) lo=mid+1; else hi=mid; }
  const int end = lo;

  __shared__ float red[256];
  __shared__ float s_max, s_inv;
  float mx = -INFINITY;
  for (int n = start+tid; n < end; n += 256) mx = fmaxf(mx, gatebuf[n]);
  red[tid]=mx; __syncthreads();
  for (int s=128; s>=1; s>>=1){ if (tid<s) red[tid]=fmaxf(red[tid],red[tid+s]); __syncthreads(); }
  if (tid==0) s_max = red[0];
  __syncthreads();
  const float gmax = s_max;
  float sum = 0.f;
  for (int n = start+tid; n < end; n += 256){
    float e = expf(gatebuf[n]-gmax);
    gatebuf[n] = e;
    sum += e;
  }
  red[tid]=sum; __syncthreads();
  for (int s=128; s>=1; s>>=1){ if (tid<s) red[tid]+=red[tid+s]; __syncthreads(); }
  if (tid==0) s_inv = 1.0f/(red[0] + 1e-16f);
  __syncthreads();
  const float inv = s_inv;
  for (int n = start+tid; n < end; n += 256) gate_out[n] = gatebuf[n]*inv;
  if (tid < 80){
    const u32* h32 = (const u32*)hb;
    float acc0 = 0.f, acc1 = 0.f;
    for (int n = start; n < end; ++n){
      u32 v = h32[(size_t)n*80 + tid];
      float gv = gatebuf[n];
      acc0 = fmaf(gv, bf2f(v & 0xffffu), acc0);
      acc1 = fmaf(gv, bf2f(v >> 16),     acc1);
    }
    int c0 = 2*tid, c1 = 2*tid + 1;
    if (c0 < H) out[g*H + c0] = acc0*inv;
    if (c1 < H) out[g*H + c1] = acc1*inv;
  }
}

extern "C" void kernel_launch(void* const* d_in, const int* in_sizes, int n_in,
                              void* d_out, int out_size, void* d_ws, size_t ws_size,
                              hipStream_t stream) {
  (void)in_sizes; (void)n_in; (void)out_size; (void)ws_size;
  const float* x    = (const float*)d_in[0];
  const int*   eidx = (const int*)d_in[1];
  const int*   batch= (const int*)d_in[2];
  const float* W    = (const float*)d_in[3];
  const float* wih  = (const float*)d_in[4];
  const float* whh  = (const float*)d_in[5];
  const float* bih  = (const float*)d_in[6];
  const float* bhh  = (const float*)d_in[7];
  const float* gw1  = (const float*)d_in[8];
  const float* gb1  = (const float*)d_in[9];
  const float* gw2  = (const float*)d_in[10];
  const float* gb2  = (const float*)d_in[11];

  float* out      = (float*)d_out;
  float* gate_out = out + NG*H;

  char* p = (char*)d_ws;
  float* gbuf  = (float*)p;  p += (size_t)NN*4;
  float* Wc    = (float*)p;  p += (size_t)NL*H*450*4;
  short* hb0   = (short*)p;  p += (size_t)(NN+1)*HS*2;
  short* hb1   = (short*)p;  p += (size_t)(NN+1)*HS*2;
  short* aggb  = (short*)p;  p += (size_t)NN*HS*2;
  short* wbi   = (short*)p;  p += (size_t)NL*76800*2;
  short* wbh   = (short*)p;  p += (size_t)76800*2;
  short* gw1b  = (short*)p;  p += (size_t)33280*2;
  int*   cnt   = (int*)p;    p += (size_t)NN*4;
  int*   rowptr= (int*)p;    p += (size_t)(NN+1)*4;
  int*   cursor= (int*)p;    p += (size_t)NN*4;
  int*   csr   = (int*)p;    p += (size_t)CSRMAX*4;
  int*   spart = (int*)p;    p += (size_t)SNB*4;
  int*   bcnt  = (int*)p;    p += (size_t)NB*4;
  int*   bcur  = (int*)p;    p += (size_t)NB*4;
  int2*  ebuf  = (int2*)p;   p += (size_t)NE*8;

  const int* esrc = eidx;
  const int* edst = eidx + NE;

  hipMemsetAsync(cnt, 0, sizeof(int)*NN, stream);
  hipMemsetAsync(bcnt, 0, sizeof(int)*NB, stream);
  k_hist<<<(NE+255)/256, 256, 0, stream>>>(edst, cnt);
  k_scan1<<<SNB, 256, 0, stream>>>(cnt, spart);
  k_scan2<<<1, 64, 0, stream>>>(spart);
  k_scan3<<<SNB, 1024, 0, stream>>>(cnt, spart, rowptr, cursor);
  k_pre <<<CSRMAX/1024, 256, 0, stream>>>(csr);
  k_bhist<<<EBLK, 256, 0, stream>>>(edst, bcnt);
  k_bscan<<<1, 256, 0, stream>>>(bcnt, bcur);
  k_bscatter<<<EBLK, 256, 0, stream>>>(esrc, edst, bcur, ebuf);
  k_fill2<<<(NE+255)/256, 256, 0, stream>>>(ebuf, cursor, csr);

  k_wc   <<<(NL*H*450+255)/256, 256, 0, stream>>>(W, wih, Wc);
  k_packi<<<1500, 256, 0, stream>>>(Wc, wbi);
  k_packh<<<300,  256, 0, stream>>>(whh, wbh);
  k_packg<<<130,  256, 0, stream>>>(gw1, gw1b);

  k_cvt<<<(NN*80+255)/256, 256, 0, stream>>>(x, hb0);
  k_zrow<<<1, 128, 0, stream>>>(hb0, hb1);

  for (int l = 0; l < NL; ++l){
    short* cur  = (l & 1) ? hb1 : hb0;
    short* next = (l & 1) ? hb0 : hb1;
    k_gather<<<NN/4, 256, 0, stream>>>(cur, rowptr, csr, aggb);
    k_gru<<<CH2, 256, 0, stream>>>(aggb, cur, next,
                                   wbi + (size_t)l*76800, wbh, bih, bhh);
  }
  k_gatepre<<<CHN, 256, 0, stream>>>(hb1, gw1b, gb1, gw2, gb2, gbuf);
  k_readout<<<NG, 256, 0, stream>>>(gbuf, hb1, batch, out, gate_out);
}

// Round 11
// 1144.979 us; speedup vs baseline: 3.1035x; 1.0760x over previous
//
#include <hip/hip_runtime.h>
#include <math.h>

#define NN 100000
#define NE 1600000
#define H 150
#define NG 256
#define NL 5
#define GH 200
#define HS 160          // padded bf16 row stride (elements)
#define LS 168          // LDS row stride in bf16 elems (gatepre)
#define CHN 1563        // ceil(NN/64)
#define CH2 782         // ceil(NN/128)
#define SNB 98          // ceil(NN/1024)
#define CSRMAX 2304000  // >= NE + 7*NN, divisible by 1024
#define NB 196          // buckets of 512 nodes
#define EBLK 782        // ceil(NE/2048)

typedef unsigned short u16;
typedef unsigned int   u32;
typedef __attribute__((ext_vector_type(8))) short bf16x8;
typedef __attribute__((ext_vector_type(4))) float f32x4;

__device__ __forceinline__ float bf2f(u32 lo16){ u32 t = lo16 << 16; return __builtin_bit_cast(float, t); }
__device__ __forceinline__ u16 f2bf(float f){
  u32 u = __builtin_bit_cast(u32, f);
  u += 0x7fffu + ((u >> 16) & 1u);
  return (u16)(u >> 16);
}
__device__ __forceinline__ u32 pack2(float a, float b){ return (u32)f2bf(a) | ((u32)f2bf(b) << 16); }
__device__ __forceinline__ float fast_sig(float x){
  float e = __expf(-x);
  return __builtin_amdgcn_rcpf(1.f + e);
}
__device__ __forceinline__ float fast_tanh(float x){
  float cx = fminf(fmaxf(x, -15.f), 15.f);
  float e = __expf(2.f*cx);
  return (e - 1.f) * __builtin_amdgcn_rcpf(e + 1.f);
}

// ---- CSR build ----
__global__ void k_hist(const int* __restrict__ ed, int* __restrict__ cnt){
  int e = blockIdx.x*256 + threadIdx.x;
  if (e < NE) atomicAdd(&cnt[ed[e]], 1);
}

// padded partial sums: sum of (cnt+7)&~7 per 1024-chunk
__global__ __launch_bounds__(256) void k_scan1(const int* __restrict__ cnt, int* __restrict__ part){
  __shared__ int red[256];
  const int b = blockIdx.x, tid = threadIdx.x;
  const int base = b*1024;
  int s = 0;
  #pragma unroll
  for (int i = 0; i < 4; ++i){
    int idx = base + tid + i*256;
    int v = (idx < NN) ? cnt[idx] : 0;
    s += (v + 7) & ~7;
  }
  red[tid] = s; __syncthreads();
  for (int st = 128; st >= 1; st >>= 1){
    if (tid < st) red[tid] += red[tid+st];
    __syncthreads();
  }
  if (tid == 0) part[b] = red[0];
}

__global__ void k_scan2(int* __restrict__ part){
  const int t = threadIdx.x;
  int v0 = (2*t   < SNB) ? part[2*t]   : 0;
  int v1 = (2*t+1 < SNB) ? part[2*t+1] : 0;
  int s = v0 + v1, x = s;
  #pragma unroll
  for (int off = 1; off < 64; off <<= 1){
    int tt = __shfl_up(x, off);
    if (t >= off) x += tt;
  }
  int excl = x - s;
  if (2*t   < SNB) part[2*t]   = excl;
  if (2*t+1 < SNB) part[2*t+1] = excl + v0;
}

// padded local scan -> rowptr (padded), cursor (padded segment start)
__global__ __launch_bounds__(1024) void k_scan3(const int* __restrict__ cnt,
        const int* __restrict__ part, int* __restrict__ rowptr, int* __restrict__ cursor){
  __shared__ int wsum[16];
  const int b = blockIdx.x, tid = threadIdx.x;
  const int wid = tid >> 6, lane = tid & 63;
  const int idx = b*1024 + tid;
  int c = (idx < NN) ? cnt[idx] : 0;
  int v = (c + 7) & ~7;
  int x = v;
  #pragma unroll
  for (int off = 1; off < 64; off <<= 1){
    int t = __shfl_up(x, off);
    if (lane >= off) x += t;
  }
  if (lane == 63) wsum[wid] = x;
  __syncthreads();
  if (tid < 16){
    int s = wsum[tid];
    int y = s;
    #pragma unroll
    for (int off = 1; off < 16; off <<= 1){
      int t = __shfl_up(y, off);
      if (tid >= off) y += t;
    }
    wsum[tid] = y - s;
  }
  __syncthreads();
  if (idx < NN){
    int incl = part[b] + wsum[wid] + x;
    rowptr[idx+1] = incl;
    cursor[idx]   = incl - v;
  }
  if (idx == 0) rowptr[0] = 0;
}

// prefill csr with dummy index NN (coalesced int4 stores)
__global__ __launch_bounds__(256) void k_pre(int* __restrict__ csr){
  int i = (blockIdx.x*256 + threadIdx.x)*4;
  int4 v = {NN, NN, NN, NN};
  *(int4*)&csr[i] = v;
}

// ---- bucket sort of edges by dst>>9 (write-locality for csr fill) ----
__global__ __launch_bounds__(256) void k_bhist(const int* __restrict__ ed, int* __restrict__ bcnt){
  __shared__ int bh[NB];
  const int tid = threadIdx.x;
  for (int i = tid; i < NB; i += 256) bh[i] = 0;
  __syncthreads();
  const int base = blockIdx.x*2048;
  #pragma unroll
  for (int i = 0; i < 8; ++i){
    int e = base + i*256 + tid;
    if (e < NE) atomicAdd(&bh[ed[e] >> 9], 1);
  }
  __syncthreads();
  for (int i = tid; i < NB; i += 256) if (bh[i]) atomicAdd(&bcnt[i], bh[i]);
}

__global__ void k_bscan(const int* __restrict__ bcnt, int* __restrict__ bcur){
  __shared__ int ws[4];
  const int t = threadIdx.x, lane = t & 63, w = t >> 6;
  int v = (t < NB) ? bcnt[t] : 0;
  int x = v;
  #pragma unroll
  for (int off = 1; off < 64; off <<= 1){
    int tt = __shfl_up(x, off);
    if (lane >= off) x += tt;
  }
  if (lane == 63) ws[w] = x;
  __syncthreads();
  if (t == 0){
    int s = 0;
    #pragma unroll
    for (int i = 0; i < 4; ++i){ int tmp = ws[i]; ws[i] = s; s += tmp; }
  }
  __syncthreads();
  if (t < NB) bcur[t] = ws[w] + x - v;
}

__global__ __launch_bounds__(256) void k_bscatter(const int* __restrict__ es,
        const int* __restrict__ ed, int* __restrict__ bcur, int2* __restrict__ ebuf){
  __shared__ int lh[NB];
  __shared__ int lbase[NB];
  const int tid = threadIdx.x;
  for (int i = tid; i < NB; i += 256) lh[i] = 0;
  __syncthreads();
  const int base = blockIdx.x*2048;
  u32 meta[8]; int srcs[8], dsts[8];
  #pragma unroll
  for (int i = 0; i < 8; ++i){
    int e = base + i*256 + tid;
    if (e < NE){
      int d = ed[e];
      int b = d >> 9;
      int lr = atomicAdd(&lh[b], 1);
      meta[i] = ((u32)b << 16) | (u32)lr;
      srcs[i] = es[e]; dsts[i] = d;
    } else meta[i] = 0xffffffffu;
  }
  __syncthreads();
  for (int i = tid; i < NB; i += 256){
    int c = lh[i];
    lbase[i] = c ? atomicAdd(&bcur[i], c) : 0;
  }
  __syncthreads();
  #pragma unroll
  for (int i = 0; i < 8; ++i){
    if (meta[i] != 0xffffffffu){
      int b = meta[i] >> 16, lr = meta[i] & 0xffff;
      ebuf[lbase[b] + lr] = make_int2(srcs[i], dsts[i]);
    }
  }
}

// consume bucket-grouped edges: csr writes land in ~40KB windows -> L2-merged
__global__ void k_fill2(const int2* __restrict__ ebuf, int* __restrict__ cursor,
                        int* __restrict__ csr){
  int e = blockIdx.x*256 + threadIdx.x;
  if (e < NE){
    int2 sd = ebuf[e];
    int pos = atomicAdd(&cursor[sd.y], 1);
    csr[pos] = sd.x;
  }
}

// ---- weight prep ----
__global__ __launch_bounds__(256) void k_wc(const float* __restrict__ W,
        const float* __restrict__ wih, float* __restrict__ Wc){
  int idx = blockIdx.x*256 + threadIdx.x;
  if (idx >= NL*H*450) return;
  int l = idx / (H*450);
  int rem = idx - l*H*450;
  int k = rem / 450;
  int j = rem - k*450;
  const float* Wr = W   + (size_t)l*H*H + (size_t)k*H;
  const float* wr = wih + (size_t)j*H;
  float acc = 0.f;
  for (int t = 0; t < H; ++t) acc = fmaf(Wr[t], wr[t], acc);
  Wc[idx] = acc;
}

__global__ void k_packi(const float* __restrict__ Wc, short* __restrict__ wbi){
  int idx = blockIdx.x*256 + threadIdx.x;    // NL*10*5*3*512
  int li = idx & 511;
  int q = idx >> 9;
  int mat = q % 3; q /= 3;
  int ks = q % 5;  q /= 5;
  int ct = q % 10; int l = q / 10;
  int lane = li >> 3, j = li & 7;
  int k = ks*32 + ((lane >> 4) << 3) + j;
  int col = ct*16 + (lane & 15);
  float v = (k < H && col < H) ? Wc[(size_t)l*H*450 + (size_t)k*450 + mat*H + col] : 0.f;
  wbi[idx] = (short)f2bf(v);
}

__global__ void k_packh(const float* __restrict__ whh, short* __restrict__ wbh){
  int idx = blockIdx.x*256 + threadIdx.x;    // 10*5*3*512
  int li = idx & 511;
  int q = idx >> 9;
  int mat = q % 3; q /= 3;
  int ks = q % 5;  int ct = q / 5;
  int lane = li >> 3, j = li & 7;
  int k = ks*32 + ((lane >> 4) << 3) + j;
  int col = ct*16 + (lane & 15);
  float v = (k < H && col < H) ? whh[(size_t)(mat*H + col)*H + k] : 0.f;
  wbh[idx] = (short)f2bf(v);
}

__global__ void k_packg(const float* __restrict__ gw1, short* __restrict__ gw1b){
  int idx = blockIdx.x*256 + threadIdx.x;    // 13*5*512
  int li = idx & 511;
  int q = idx >> 9;
  int ks = q % 5;  int ct = q / 5;
  int lane = li >> 3, j = li & 7;
  int k = ks*32 + ((lane >> 4) << 3) + j;
  int col = ct*16 + (lane & 15);
  float v = (k < H && col < GH) ? gw1[(size_t)k*GH + col] : 0.f;
  gw1b[idx] = (short)f2bf(v);
}

__global__ void k_cvt(const float* __restrict__ x, short* __restrict__ hb){
  int idx = blockIdx.x*256 + threadIdx.x;    // NN*80
  if (idx >= NN*80) return;
  int n = idx / 80, c2 = idx - n*80;
  int c = c2*2;
  float lo = (c   < H) ? x[(size_t)n*H + c]   : 0.f;
  float hi = (c+1 < H) ? x[(size_t)n*H + c+1] : 0.f;
  ((u32*)hb)[idx] = (u32)f2bf(lo) | ((u32)f2bf(hi) << 16);
}

// zero the dummy row NN in both state buffers
__global__ void k_zrow(short* __restrict__ a, short* __restrict__ b){
  int t = threadIdx.x;
  if (t < 80){
    ((u32*)a)[(size_t)NN*80 + t] = 0u;
    ((u32*)b)[(size_t)NN*80 + t] = 0u;
  }
}

// aggb[n] = sum over padded segment (pads hit zero dummy row) — no tail loop
__global__ __launch_bounds__(256) void k_gather(const short* __restrict__ hb,
        const int* __restrict__ rowptr, const int* __restrict__ csr,
        short* __restrict__ aggb){
  const int lane = threadIdx.x & 63;
  const int n = blockIdx.x*4 + (threadIdx.x >> 6);
  if (n >= NN) return;
  const int s0 = rowptr[n], s1 = rowptr[n+1];
  const u32* h32 = (const u32*)hb;
  const bool ext = lane < 16;
  float x0=0.f, x1=0.f, y0=0.f, y1=0.f;
  for (int j = s0; j < s1; j += 8){
    int4 ia = *(const int4*)&csr[j];
    int4 ib = *(const int4*)&csr[j+4];
    const u32* r0 = h32 + (size_t)ia.x*80;
    const u32* r1 = h32 + (size_t)ia.y*80;
    const u32* r2 = h32 + (size_t)ia.z*80;
    const u32* r3 = h32 + (size_t)ia.w*80;
    const u32* r4 = h32 + (size_t)ib.x*80;
    const u32* r5 = h32 + (size_t)ib.y*80;
    const u32* r6 = h32 + (size_t)ib.z*80;
    const u32* r7 = h32 + (size_t)ib.w*80;
    u32 v0 = r0[lane], v1 = r1[lane], v2 = r2[lane], v3 = r3[lane];
    u32 v4 = r4[lane], v5 = r5[lane], v6 = r6[lane], v7 = r7[lane];
    u32 u0=0,u1=0,u2=0,u3=0,u4=0,u5=0,u6=0,u7=0;
    if (ext){
      u0 = r0[64+lane]; u1 = r1[64+lane]; u2 = r2[64+lane]; u3 = r3[64+lane];
      u4 = r4[64+lane]; u5 = r5[64+lane]; u6 = r6[64+lane]; u7 = r7[64+lane];
    }
    x0 += bf2f(v0 & 0xffffu) + bf2f(v1 & 0xffffu) + bf2f(v2 & 0xffffu) + bf2f(v3 & 0xffffu)
        + bf2f(v4 & 0xffffu) + bf2f(v5 & 0xffffu) + bf2f(v6 & 0xffffu) + bf2f(v7 & 0xffffu);
    x1 += bf2f(v0 >> 16) + bf2f(v1 >> 16) + bf2f(v2 >> 16) + bf2f(v3 >> 16)
        + bf2f(v4 >> 16) + bf2f(v5 >> 16) + bf2f(v6 >> 16) + bf2f(v7 >> 16);
    if (ext){
      y0 += bf2f(u0 & 0xffffu) + bf2f(u1 & 0xffffu) + bf2f(u2 & 0xffffu) + bf2f(u3 & 0xffffu)
          + bf2f(u4 & 0xffffu) + bf2f(u5 & 0xffffu) + bf2f(u6 & 0xffffu) + bf2f(u7 & 0xffffu);
      y1 += bf2f(u0 >> 16) + bf2f(u1 >> 16) + bf2f(u2 >> 16) + bf2f(u3 >> 16)
          + bf2f(u4 >> 16) + bf2f(u5 >> 16) + bf2f(u6 >> 16) + bf2f(u7 >> 16);
    }
  }
  u32* o = (u32*)aggb + (size_t)n*80;
  o[lane] = pack2(x0, x1);
  if (ext) o[64+lane] = pack2(y0, y1);
}

// ---- GRU via MFMA; A/H in registers, B double-buffered via LDS (1 barrier/ct) ----
__global__ __launch_bounds__(256, 2) void k_gru(
    const short* __restrict__ aggb, const short* __restrict__ hbc,
    short* __restrict__ hbn,
    const short* __restrict__ wbi_l, const short* __restrict__ wbh,
    const float* __restrict__ bih, const float* __restrict__ bhh){
  __shared__ short sB[2][15360];   // per buf: slots 0..14 gi, 15..29 gh (512 elems each)
  const int tid = threadIdx.x;
  const int w = tid >> 6, lane = tid & 63;
  const int l16 = lane & 15, g = lane >> 4, g8 = g*8;
  const int row0 = blockIdx.x*128 + w*32;

  bf16x8 fA[2][5], fH[2][5];
  #pragma unroll
  for (int t = 0; t < 2; ++t){
    const int r = row0 + t*16 + l16;
    const bool rv = r < NN;
    #pragma unroll
    for (int ks = 0; ks < 5; ++ks){
      bf16x8 va = {0,0,0,0,0,0,0,0}, vh = {0,0,0,0,0,0,0,0};
      if (rv){
        va = *(const bf16x8*)&aggb[(size_t)r*HS + ks*32 + g8];
        vh = *(const bf16x8*)&hbc [(size_t)r*HS + ks*32 + g8];
      }
      fA[t][ks] = va; fH[t][ks] = vh;
    }
  }

  bf16x8 pr[8];
  // prologue: stage ct=0 into sB[0]
  #pragma unroll
  for (int k2 = 0; k2 < 8; ++k2){
    int u = tid + k2*256;
    if (u < 1920){
      int s = u >> 6, e = u & 63;
      const short* src = (s < 15) ? (wbi_l + s*512 + e*8)
                                  : (wbh  + (s-15)*512 + e*8);
      pr[k2] = *(const bf16x8*)src;
    }
  }
  #pragma unroll
  for (int k2 = 0; k2 < 8; ++k2){
    int u = tid + k2*256;
    if (u < 1920) *(bf16x8*)&sB[0][u*8] = pr[k2];
  }

  for (int ct = 0; ct < 10; ++ct){
    const int cur = ct & 1;
    __syncthreads();   // sB[cur] written; prior readers of sB[cur^1] done
    if (ct < 9){
      const int cto = (ct+1)*7680;
      #pragma unroll
      for (int k2 = 0; k2 < 8; ++k2){
        int u = tid + k2*256;
        if (u < 1920){
          int s = u >> 6, e = u & 63;
          const short* src = (s < 15) ? (wbi_l + cto + s*512 + e*8)
                                      : (wbh  + cto + (s-15)*512 + e*8);
          pr[k2] = *(const bf16x8*)src;
        }
      }
    }

    const int col = ct*16 + l16;
    const bool cv = col < H;
    const float bir = cv ? bih[col] : 0.f, biz = cv ? bih[H+col] : 0.f, bin_ = cv ? bih[2*H+col] : 0.f;
    const float bhr = cv ? bhh[col] : 0.f, bhz = cv ? bhh[H+col] : 0.f, bhn  = cv ? bhh[2*H+col] : 0.f;

    f32x4 ai[2][3], ah[2][3];
    #pragma unroll
    for (int t = 0; t < 2; ++t)
      #pragma unroll
      for (int m = 0; m < 3; ++m){ ai[t][m] = (f32x4){0,0,0,0}; ah[t][m] = (f32x4){0,0,0,0}; }

    const short* sbc = sB[cur];
    #pragma unroll
    for (int ks = 0; ks < 5; ++ks){
      bf16x8 bi0 = *(const bf16x8*)&sbc[(ks*3+0)*512 + lane*8];
      bf16x8 bi1 = *(const bf16x8*)&sbc[(ks*3+1)*512 + lane*8];
      bf16x8 bi2 = *(const bf16x8*)&sbc[(ks*3+2)*512 + lane*8];
      bf16x8 bh0 = *(const bf16x8*)&sbc[(15+ks*3+0)*512 + lane*8];
      bf16x8 bh1 = *(const bf16x8*)&sbc[(15+ks*3+1)*512 + lane*8];
      bf16x8 bh2 = *(const bf16x8*)&sbc[(15+ks*3+2)*512 + lane*8];
      #pragma unroll
      for (int t = 0; t < 2; ++t){
        ai[t][0] = __builtin_amdgcn_mfma_f32_16x16x32_bf16(fA[t][ks], bi0, ai[t][0], 0,0,0);
        ai[t][1] = __builtin_amdgcn_mfma_f32_16x16x32_bf16(fA[t][ks], bi1, ai[t][1], 0,0,0);
        ai[t][2] = __builtin_amdgcn_mfma_f32_16x16x32_bf16(fA[t][ks], bi2, ai[t][2], 0,0,0);
        ah[t][0] = __builtin_amdgcn_mfma_f32_16x16x32_bf16(fH[t][ks], bh0, ah[t][0], 0,0,0);
        ah[t][1] = __builtin_amdgcn_mfma_f32_16x16x32_bf16(fH[t][ks], bh1, ah[t][1], 0,0,0);
        ah[t][2] = __builtin_amdgcn_mfma_f32_16x16x32_bf16(fH[t][ks], bh2, ah[t][2], 0,0,0);
      }
    }

    if (ct < 9){
      #pragma unroll
      for (int k2 = 0; k2 < 8; ++k2){
        int u = tid + k2*256;
        if (u < 1920) *(bf16x8*)&sB[cur^1][u*8] = pr[k2];
      }
    }

    if (cv){
      #pragma unroll
      for (int t = 0; t < 2; ++t){
        #pragma unroll
        for (int r = 0; r < 4; ++r){
          int grow = row0 + t*16 + g*4 + r;
          if (grow < NN){
            float rr = fast_sig(ai[t][0][r]+bir + ah[t][0][r]+bhr);
            float zz = fast_sig(ai[t][1][r]+biz + ah[t][1][r]+bhz);
            float nn = fast_tanh(ai[t][2][r]+bin_ + rr*(ah[t][2][r]+bhn));
            float hold = bf2f((u32)(u16)hbc[(size_t)grow*HS + col]);
            float hnew = (1.f-zz)*nn + zz*hold;
            hbn[(size_t)grow*HS + col] = (short)f2bf(hnew);
          }
        }
      }
    }
  }
}

// gate_pre via MFMA
__global__ __launch_bounds__(256) void k_gatepre(const short* __restrict__ hb,
      const short* __restrict__ gw1b, const float* __restrict__ gb1,
      const float* __restrict__ gw2, const float* __restrict__ gb2,
      float* __restrict__ gbuf){
  __shared__ short sh[64*LS];
  __shared__ float part[4][4][4][4];
  const int tid = threadIdx.x;
  const int w = tid >> 6, lane = tid & 63;
  const int l16 = lane & 15, g = lane >> 4, g8 = g*8;
  const int chunk = blockIdx.x, row0 = chunk*64;

  for (int i = tid; i < 64*20; i += 256){
    int r = i/20, c = i - r*20;
    int gr = row0 + r;
    bf16x8 v = {0,0,0,0,0,0,0,0};
    if (gr < NN) v = *(const bf16x8*)&hb[(size_t)gr*HS + c*8];
    *(bf16x8*)&sh[r*LS + c*8] = v;
  }
  __syncthreads();

  float acc[4][4];
  #pragma unroll
  for (int rt=0; rt<4; ++rt){
    #pragma unroll
    for (int r=0; r<4; ++r) acc[rt][r] = 0.f;
  }
  for (int ct = w; ct < 13; ct += 4){
    bf16x8 B[5];
    const short* p = gw1b + (size_t)(ct*5)*512 + lane*8;
    #pragma unroll
    for (int ks = 0; ks < 5; ++ks) B[ks] = *(const bf16x8*)&p[ks*512];
    int col = ct*16 + l16;
    bool cv = col < GH;
    float g2 = cv ? gw2[col] : 0.f;
    float b1 = cv ? gb1[col] : 0.f;
    #pragma unroll
    for (int rt = 0; rt < 4; ++rt){
      f32x4 d = {0,0,0,0};
      #pragma unroll
      for (int ks = 0; ks < 5; ++ks){
        bf16x8 aH = *(const bf16x8*)&sh[(rt*16 + l16)*LS + ks*32 + g8];
        d = __builtin_amdgcn_mfma_f32_16x16x32_bf16(aH, B[ks], d, 0,0,0);
      }
      if (cv){
        #pragma unroll
        for (int r = 0; r < 4; ++r) acc[rt][r] += fast_tanh(d[r] + b1) * g2;
      }
    }
  }
  #pragma unroll
  for (int rt = 0; rt < 4; ++rt){
    #pragma unroll
    for (int r = 0; r < 4; ++r){
      float v = acc[rt][r];
      v += __shfl_xor(v, 1); v += __shfl_xor(v, 2);
      v += __shfl_xor(v, 4); v += __shfl_xor(v, 8);
      if (l16 == 0) part[w][rt][g][r] = v;
    }
  }
  __syncthreads();
  if (tid < 64){
    int rt = tid >> 4, gg = (tid >> 2) & 3, r = tid & 3;
    int grow = row0 + tid;
    if (grow < NN)
      gbuf[grow] = part[0][rt][gg][r] + part[1][rt][gg][r]
                 + part[2][rt][gg][r] + part[3][rt][gg][r] + gb2[0];
  }
}

// per-graph segment softmax + weighted sum (bf16 h)
// 512 threads; weighted sum = 80 cols x 6 node-groups (deterministic LDS reduce)
__global__ __launch_bounds__(512) void k_readout(float* __restrict__ gatebuf,
    const short* __restrict__ hb, const int* __restrict__ batch,
    float* __restrict__ out, float* __restrict__ gate_out){
  const int g = blockIdx.x;
  const int tid = threadIdx.x;
  int lo=0, hi=NN;
  while (lo<hi){ int mid=(lo+hi)>>1; if (batch[mid] < g) lo=mid+1; else hi=mid; }
  const int start = lo;
  hi = NN;
  while (lo<hi){ int mid=(lo+hi)>>1; if (batch[mid] < g+1) lo=mid+1; else hi=mid; }
  const int end = lo;

  __shared__ float red[512];
  __shared__ float pacc[6][80][2];
  __shared__ float s_max, s_inv;
  float mx = -INFINITY;
  for (int n = start+tid; n < end; n += 512) mx = fmaxf(mx, gatebuf[n]);
  red[tid]=mx; __syncthreads();
  for (int s=256; s>=1; s>>=1){ if (tid<s) red[tid]=fmaxf(red[tid],red[tid+s]); __syncthreads(); }
  if (tid==0) s_max = red[0];
  __syncthreads();
  const float gmax = s_max;
  float sum = 0.f;
  for (int n = start+tid; n < end; n += 512){
    float e = expf(gatebuf[n]-gmax);
    gatebuf[n] = e;
    sum += e;
  }
  red[tid]=sum; __syncthreads();
  for (int s=256; s>=1; s>>=1){ if (tid<s) red[tid]+=red[tid+s]; __syncthreads(); }
  if (tid==0) s_inv = 1.0f/(red[0] + 1e-16f);
  __syncthreads();
  const float inv = s_inv;
  for (int n = start+tid; n < end; n += 512) gate_out[n] = gatebuf[n]*inv;

  // weighted sum: col = tid%80, group = tid/80 (6 groups of 80, 480 active)
  const int col = tid % 80;
  const int grp = tid / 80;
  const u32* h32 = (const u32*)hb;
  if (grp < 6){
    float a0 = 0.f, a1 = 0.f;
    for (int n = start + grp; n < end; n += 6){
      u32 v = h32[(size_t)n*80 + col];
      float gv = gatebuf[n];
      a0 = fmaf(gv, bf2f(v & 0xffffu), a0);
      a1 = fmaf(gv, bf2f(v >> 16),     a1);
    }
    pacc[grp][col][0] = a0;
    pacc[grp][col][1] = a1;
  }
  __syncthreads();
  if (tid < 80){
    float a0 = 0.f, a1 = 0.f;
    #pragma unroll
    for (int q = 0; q < 6; ++q){ a0 += pacc[q][tid][0]; a1 += pacc[q][tid][1]; }
    int c0 = 2*tid, c1 = 2*tid + 1;
    if (c0 < H) out[g*H + c0] = a0*inv;
    if (c1 < H) out[g*H + c1] = a1*inv;
  }
}

extern "C" void kernel_launch(void* const* d_in, const int* in_sizes, int n_in,
                              void* d_out, int out_size, void* d_ws, size_t ws_size,
                              hipStream_t stream) {
  (void)in_sizes; (void)n_in; (void)out_size; (void)ws_size;
  const float* x    = (const float*)d_in[0];
  const int*   eidx = (const int*)d_in[1];
  const int*   batch= (const int*)d_in[2];
  const float* W    = (const float*)d_in[3];
  const float* wih  = (const float*)d_in[4];
  const float* whh  = (const float*)d_in[5];
  const float* bih  = (const float*)d_in[6];
  const float* bhh  = (const float*)d_in[7];
  const float* gw1  = (const float*)d_in[8];
  const float* gb1  = (const float*)d_in[9];
  const float* gw2  = (const float*)d_in[10];
  const float* gb2  = (const float*)d_in[11];

  float* out      = (float*)d_out;
  float* gate_out = out + NG*H;

  char* p = (char*)d_ws;
  float* gbuf  = (float*)p;  p += (size_t)NN*4;
  float* Wc    = (float*)p;  p += (size_t)NL*H*450*4;
  short* hb0   = (short*)p;  p += (size_t)(NN+1)*HS*2;
  short* hb1   = (short*)p;  p += (size_t)(NN+1)*HS*2;
  short* aggb  = (short*)p;  p += (size_t)NN*HS*2;
  short* wbi   = (short*)p;  p += (size_t)NL*76800*2;
  short* wbh   = (short*)p;  p += (size_t)76800*2;
  short* gw1b  = (short*)p;  p += (size_t)33280*2;
  int*   cnt   = (int*)p;    p += (size_t)NN*4;
  int*   rowptr= (int*)p;    p += (size_t)(NN+1)*4;
  int*   cursor= (int*)p;    p += (size_t)NN*4;
  int*   csr   = (int*)p;    p += (size_t)CSRMAX*4;
  int*   spart = (int*)p;    p += (size_t)SNB*4;
  int*   bcnt  = (int*)p;    p += (size_t)NB*4;
  int*   bcur  = (int*)p;    p += (size_t)NB*4;
  int2*  ebuf  = (int2*)p;   p += (size_t)NE*8;

  const int* esrc = eidx;
  const int* edst = eidx + NE;

  hipMemsetAsync(cnt, 0, sizeof(int)*NN, stream);
  hipMemsetAsync(bcnt, 0, sizeof(int)*NB, stream);
  k_hist<<<(NE+255)/256, 256, 0, stream>>>(edst, cnt);
  k_scan1<<<SNB, 256, 0, stream>>>(cnt, spart);
  k_scan2<<<1, 64, 0, stream>>>(spart);
  k_scan3<<<SNB, 1024, 0, stream>>>(cnt, spart, rowptr, cursor);
  k_pre <<<CSRMAX/1024, 256, 0, stream>>>(csr);
  k_bhist<<<EBLK, 256, 0, stream>>>(edst, bcnt);
  k_bscan<<<1, 256, 0, stream>>>(bcnt, bcur);
  k_bscatter<<<EBLK, 256, 0, stream>>>(esrc, edst, bcur, ebuf);
  k_fill2<<<(NE+255)/256, 256, 0, stream>>>(ebuf, cursor, csr);

  k_wc   <<<(NL*H*450+255)/256, 256, 0, stream>>>(W, wih, Wc);
  k_packi<<<1500, 256, 0, stream>>>(Wc, wbi);
  k_packh<<<300,  256, 0, stream>>>(whh, wbh);
  k_packg<<<130,  256, 0, stream>>>(gw1, gw1b);

  k_cvt<<<(NN*80+255)/256, 256, 0, stream>>>(x, hb0);
  k_zrow<<<1, 128, 0, stream>>>(hb0, hb1);

  for (int l = 0; l < NL; ++l){
    short* cur  = (l & 1) ? hb1 : hb0;
    short* next = (l & 1) ? hb0 : hb1;
    k_gather<<<NN/4, 256, 0, stream>>>(cur, rowptr, csr, aggb);
    k_gru<<<CH2, 256, 0, stream>>>(aggb, cur, next,
                                   wbi + (size_t)l*76800, wbh, bih, bhh);
  }
  k_gatepre<<<CHN, 256, 0, stream>>>(hb1, gw1b, gb1, gw2, gb2, gbuf);
  k_readout<<<NG, 512, 0, stream>>>(gbuf, hb1, batch, out, gate_out);
}